// Round 17
// baseline (6804.231 us; speedup 1.0000x reference)
//
#include <hip/hip_runtime.h>

#define L 6
#define D 1024
#define DFF 4096
#define BATCH 4
#define S 1024

typedef __attribute__((ext_vector_type(4))) float f32x4;
typedef __attribute__((ext_vector_type(8))) short short8;

__device__ __forceinline__ ushort f2bf(float f) {
    unsigned int u = __float_as_uint(f);
    u = u + 0x7FFF + ((u >> 16) & 1);
    return (ushort)(u >> 16);
}
__device__ __forceinline__ float bf2f(ushort u) {
    return __uint_as_float(((unsigned int)u) << 16);
}
__device__ __forceinline__ void gload16(const ushort* g, ushort* l) {
    __builtin_amdgcn_global_load_lds(
        (const __attribute__((address_space(1))) void*)g,
        (__attribute__((address_space(3))) void*)l, 16, 0, 0);
}

// ---------------- split f32 -> (hi, lo) bf16 planes ----------------
__global__ __launch_bounds__(256) void cvt_split(const float* __restrict__ in,
                                                 ushort* __restrict__ oh,
                                                 ushort* __restrict__ ol, int n) {
    int i = (blockIdx.x * 256 + threadIdx.x) * 4;
    if (i >= n) return;
    float4 v = *(const float4*)&in[i];
    ushort4 h, l;
    h.x = f2bf(v.x); l.x = f2bf(v.x - bf2f(h.x));
    h.y = f2bf(v.y); l.y = f2bf(v.y - bf2f(h.y));
    h.z = f2bf(v.z); l.z = f2bf(v.z - bf2f(h.z));
    h.w = f2bf(v.w); l.w = f2bf(v.w - bf2f(h.w));
    *(ushort4*)&oh[i] = h;
    *(ushort4*)&ol[i] = l;
}

// ------- transpose weight [K,N] f32 -> [N,K] h/l bf16 -------
__global__ __launch_bounds__(256) void transpose_w(const float* __restrict__ W,
                                                   ushort* __restrict__ outh,
                                                   ushort* __restrict__ outl,
                                                   int K, int N) {
    __shared__ float T[32][33];
    int n0 = blockIdx.x * 32, k0 = blockIdx.y * 32;
    int t = threadIdx.x;
    int r = t >> 3, c4 = (t & 7) * 4;
    float4 v = *(const float4*)&W[(size_t)(k0 + r) * N + n0 + c4];
    T[r][c4 + 0] = v.x; T[r][c4 + 1] = v.y; T[r][c4 + 2] = v.z; T[r][c4 + 3] = v.w;
    __syncthreads();
    float a0 = T[c4 + 0][r], a1 = T[c4 + 1][r], a2 = T[c4 + 2][r], a3 = T[c4 + 3][r];
    ushort4 h, l;
    h.x = f2bf(a0); l.x = f2bf(a0 - bf2f(h.x));
    h.y = f2bf(a1); l.y = f2bf(a1 - bf2f(h.y));
    h.z = f2bf(a2); l.z = f2bf(a2 - bf2f(h.z));
    h.w = f2bf(a3); l.w = f2bf(a3 - bf2f(h.w));
    size_t ob = (size_t)(n0 + r) * K + k0 + c4;
    *(ushort4*)&outh[ob] = h;
    *(ushort4*)&outl[ob] = l;
}

// ---------------- transpose vo planes [b][s][2048-strided] -> [b][d][s] ----------------
__global__ __launch_bounds__(256) void vtrans(const ushort* __restrict__ inh,
                                              const ushort* __restrict__ inl,
                                              ushort* __restrict__ outh,
                                              ushort* __restrict__ outl,
                                              int ld_in, int col_off) {
    __shared__ ushort T[32][40];
    const int pz = blockIdx.z, b = pz >> 1;
    const ushort* in = (pz & 1) ? inl : inh;
    ushort* out = (pz & 1) ? outl : outh;
    const int d0 = blockIdx.x * 32, s0 = blockIdx.y * 32;
    const int t = threadIdx.x, r = t >> 3, c4 = (t & 7) * 4;
    ushort4 v = *(const ushort4*)&in[(size_t)(b * S + s0 + r) * ld_in + col_off + d0 + c4];
    T[r][c4 + 0] = v.x; T[r][c4 + 1] = v.y; T[r][c4 + 2] = v.z; T[r][c4 + 3] = v.w;
    __syncthreads();
    ushort4 o = {T[c4 + 0][r], T[c4 + 1][r], T[c4 + 2][r], T[c4 + 3][r]};
    *(ushort4*)&out[(size_t)(b * D + d0 + r) * S + s0 + c4] = o;
}

// -------- reduce 8 split-K f32 partials [8][1024][1024] -> h/l bf16 planes --------
__global__ __launch_bounds__(256) void reduce_split(const float* __restrict__ part,
                                                    ushort* __restrict__ oh,
                                                    ushort* __restrict__ ol) {
    int i = (blockIdx.x * 256 + threadIdx.x) * 4;
    float4 s = *(const float4*)&part[i];
#pragma unroll
    for (int z = 1; z < 8; z++) {
        float4 p = *(const float4*)&part[(size_t)z * 1048576 + i];
        s.x += p.x; s.y += p.y; s.z += p.z; s.w += p.w;
    }
    ushort4 h, l;
    h.x = f2bf(s.x); l.x = f2bf(s.x - bf2f(h.x));
    h.y = f2bf(s.y); l.y = f2bf(s.y - bf2f(h.y));
    h.z = f2bf(s.z); l.z = f2bf(s.z - bf2f(h.z));
    h.w = f2bf(s.w); l.w = f2bf(s.w - bf2f(h.w));
    *(ushort4*)&oh[i] = h;
    *(ushort4*)&ol[i] = l;
}

// -------- bias fold: out[n] = sum_j bf1[j] * Wf2[j][n] + bf2[n] --------
__global__ __launch_bounds__(256) void bias_fold(const float* __restrict__ bf1,
                                                 const float* __restrict__ Wf2,
                                                 const float* __restrict__ bf2,
                                                 float* __restrict__ out) {
    __shared__ float red[4][64];
    const int lane = threadIdx.x & 63, js = threadIdx.x >> 6;
    const int n = blockIdx.x * 64 + lane;
    float s = 0.f;
    const int j0 = js * 1024;
    for (int j = j0; j < j0 + 1024; j++) s += bf1[j] * Wf2[(size_t)j * D + n];
    red[js][lane] = s;
    __syncthreads();
    if (js == 0) out[n] = red[0][lane] + red[1][lane] + red[2][lane] + red[3][lane] + bf2[n];
}

// ---------------- gemm3: 128x128 split-precision GEMM, BK=32, 5 blocks/CU ----------------
// LDS: 4 planes x [128][32] linear (32 KiB). Swizzle: phys slot = slot ^ ((row>>1)&3),
// applied to global source col (staging) and ds_read col (fragments) - involution.
// triMode: 0 none; 1 = causal scores (skip bx>by); 2 = causal PV (cap K-tiles)
__global__ __launch_bounds__(256, 5) void gemm3(
    const ushort* __restrict__ Ah, const ushort* __restrict__ Al,
    const ushort* __restrict__ Bh, const ushort* __restrict__ Bl,
    float* __restrict__ Cf, ushort* __restrict__ Ch, ushort* __restrict__ Cl,
    const float* __restrict__ bias, float alpha,
    int M, int N, int K, int lda, int ldb, int ldc,
    long sA, long sB, long sC, int triMode) {
    __shared__ ushort lds[4 * 4096];   // 32 KiB
    ushort* Ash = lds;
    ushort* Asl = lds + 4096;
    ushort* Bsh = lds + 2 * 4096;
    ushort* Bsl = lds + 3 * 4096;

    const int gx = gridDim.x, gy = gridDim.y;
    int nblk = gx * gy * gridDim.z;
    int bid = (blockIdx.z * gy + blockIdx.y) * gx + blockIdx.x;
    if ((nblk & 7) == 0) bid = (bid & 7) * (nblk >> 3) + (bid >> 3);
    const int bx = bid % gx;
    int rem = bid / gx;
    const int by = rem % gy;
    const int z = rem / gy;

    if (triMode == 1 && bx > by) return;
    int NT = K >> 5;
    if (triMode == 2) {
        int cap = 4 * by + 4;
        if (cap < NT) NT = cap;
    }

    const int bm = by * 128, bn = bx * 128;
    const ushort* A0 = Ah + (size_t)z * sA;
    const ushort* A1 = Al + (size_t)z * sA;
    const ushort* B0 = Bh + (size_t)z * sB;
    const ushort* B1 = Bl + (size_t)z * sB;
    const size_t coff = (size_t)z * sC;

    const int tid = threadIdx.x, lane = tid & 63;
    const int wid = tid >> 6, wr = wid >> 1, wc = wid & 1;
    const int lr = lane & 15, lg = lane >> 4;

    f32x4 acc[4][4] = {};

    for (int kt = 0; kt < NT; kt++) {
        const int k0 = kt << 5;
        if (kt) __syncthreads();
#pragma unroll
        for (int c = 0; c < 2; c++) {
            const int idx = c * 256 + tid;
            const int row = idx >> 2;                       // 0..127
            const int ps = idx & 3;                         // phys 16B slot
            const int col = ((ps ^ ((row >> 1) & 3)) * 8);  // pre-swizzled source slot
            const int lbase = idx * 8;                      // linear LDS dest
            const size_t aoff = (size_t)(bm + row) * lda + k0 + col;
            const size_t boff = (size_t)(bn + row) * ldb + k0 + col;
            gload16(A0 + aoff, Ash + lbase);
            gload16(A1 + aoff, Asl + lbase);
            gload16(B0 + boff, Bsh + lbase);
            gload16(B1 + boff, Bsl + lbase);
        }
        asm volatile("s_waitcnt vmcnt(0)" ::: "memory");
        __syncthreads();
        short8 afh[4], afl[4], bfh[4], bfl[4];
#pragma unroll
        for (int i = 0; i < 4; i++) {
            const int arow = wr * 64 + i * 16 + lr;
            const int brow = wc * 64 + i * 16 + lr;
            const int ar = arow * 32 + ((lg ^ ((arow >> 1) & 3)) * 8);
            const int br = brow * 32 + ((lg ^ ((brow >> 1) & 3)) * 8);
            afh[i] = *(const short8*)&Ash[ar];
            afl[i] = *(const short8*)&Asl[ar];
            bfh[i] = *(const short8*)&Bsh[br];
            bfl[i] = *(const short8*)&Bsl[br];
        }
#pragma unroll
        for (int i = 0; i < 4; i++)
#pragma unroll
            for (int j = 0; j < 4; j++) {
                acc[i][j] = __builtin_amdgcn_mfma_f32_16x16x32_bf16(afh[i], bfh[j], acc[i][j], 0, 0, 0);
                acc[i][j] = __builtin_amdgcn_mfma_f32_16x16x32_bf16(afh[i], bfl[j], acc[i][j], 0, 0, 0);
                acc[i][j] = __builtin_amdgcn_mfma_f32_16x16x32_bf16(afl[i], bfh[j], acc[i][j], 0, 0, 0);
            }
    }
#pragma unroll
    for (int j = 0; j < 4; j++) {
        const int n = bn + wc * 64 + j * 16 + lr;
        const float bv = bias ? bias[n] : 0.f;
#pragma unroll
        for (int i = 0; i < 4; i++) {
#pragma unroll
            for (int r = 0; r < 4; r++) {
                const int m = bm + wr * 64 + i * 16 + lg * 4 + r;
                float v = acc[i][j][r] * alpha + bv;
                const size_t ci = coff + (size_t)m * ldc + n;
                if (Cf) Cf[ci] = v;
                if (Ch) {
                    ushort h = f2bf(v);
                    Ch[ci] = h;
                    Cl[ci] = f2bf(v - bf2f(h));
                }
            }
        }
    }
}

// ---------------- row softmax (f32 in, h/l bf16 planes out) ----------------
__global__ __launch_bounds__(256) void softmax_rows(const float* __restrict__ Sc,
                                                    ushort* __restrict__ Ph,
                                                    ushort* __restrict__ Pl, int causal) {
    __shared__ float red[4];
    int q = blockIdx.x, b = blockIdx.y;
    size_t base = ((size_t)b * S + q) * S;
    int valid = causal ? (q + 1) : S;
    int tid = threadIdx.x;
    float v[4];
    float mx = -3e38f;
#pragma unroll
    for (int j = 0; j < 4; j++) {
        int c = tid + j * 256;
        float x = (c < valid) ? Sc[base + c] : -3e38f;
        v[j] = x;
        mx = fmaxf(mx, v[j]);
    }
    for (int o = 32; o; o >>= 1) mx = fmaxf(mx, __shfl_xor(mx, o));
    if ((tid & 63) == 0) red[tid >> 6] = mx;
    __syncthreads();
    mx = fmaxf(fmaxf(red[0], red[1]), fmaxf(red[2], red[3]));
    float s = 0.f;
#pragma unroll
    for (int j = 0; j < 4; j++) {
        int c = tid + j * 256;
        float e = (c < valid) ? __expf(v[j] - mx) : 0.f;
        v[j] = e;
        s += e;
    }
    for (int o = 32; o; o >>= 1) s += __shfl_xor(s, o);
    __syncthreads();
    if ((tid & 63) == 0) red[tid >> 6] = s;
    __syncthreads();
    s = red[0] + red[1] + red[2] + red[3];
    float inv = 1.0f / s;
#pragma unroll
    for (int j = 0; j < 4; j++) {
        int c = tid + j * 256;
        float p = v[j] * inv;
        ushort h = f2bf(p);
        Ph[base + c] = h;
        Pl[base + c] = f2bf(p - bf2f(h));
    }
}

// ---------------- residual + layernorm (f32 in, f32 + h/l planes out) ----------------
__global__ __launch_bounds__(256) void ln_res(const float* __restrict__ xin,
                                              const float* __restrict__ y,
                                              const float* __restrict__ g,
                                              const float* __restrict__ bta,
                                              float* __restrict__ xof,
                                              ushort* __restrict__ xh,
                                              ushort* __restrict__ xl) {
    __shared__ float red[4];
    int row = blockIdx.x;
    size_t base = (size_t)row * D;
    int tid = threadIdx.x;
    int c0 = tid * 4;
    float4 xv = *(const float4*)&xin[base + c0];
    float4 yv = *(const float4*)&y[base + c0];
    float t[4] = {xv.x + yv.x, xv.y + yv.y, xv.z + yv.z, xv.w + yv.w};
    float s = t[0] + t[1] + t[2] + t[3];
    for (int o = 32; o; o >>= 1) s += __shfl_xor(s, o);
    if ((tid & 63) == 0) red[tid >> 6] = s;
    __syncthreads();
    s = red[0] + red[1] + red[2] + red[3];
    float mean = s * (1.0f / D);
    float vs = 0.f;
#pragma unroll
    for (int j = 0; j < 4; j++) {
        float dd = t[j] - mean;
        vs += dd * dd;
    }
    for (int o = 32; o; o >>= 1) vs += __shfl_xor(vs, o);
    __syncthreads();
    if ((tid & 63) == 0) red[tid >> 6] = vs;
    __syncthreads();
    vs = red[0] + red[1] + red[2] + red[3];
    float inv = rsqrtf(vs * (1.0f / D) + 1e-5f);
    float4 gv = *(const float4*)&g[c0];
    float4 bv = *(const float4*)&bta[c0];
    float o0 = (t[0] - mean) * inv * gv.x + bv.x;
    float o1 = (t[1] - mean) * inv * gv.y + bv.y;
    float o2 = (t[2] - mean) * inv * gv.z + bv.z;
    float o3 = (t[3] - mean) * inv * gv.w + bv.w;
    float4 fo = {o0, o1, o2, o3};
    *(float4*)&xof[base + c0] = fo;
    ushort4 h, l;
    h.x = f2bf(o0); l.x = f2bf(o0 - bf2f(h.x));
    h.y = f2bf(o1); l.y = f2bf(o1 - bf2f(h.y));
    h.z = f2bf(o2); l.z = f2bf(o2 - bf2f(h.z));
    h.w = f2bf(o3); l.w = f2bf(o3 - bf2f(h.w));
    *(ushort4*)&xh[base + c0] = h;
    *(ushort4*)&xl[base + c0] = l;
}

__global__ __launch_bounds__(256) void fill_f32(float* out, float v, int n) {
    int i = (blockIdx.x * 256 + threadIdx.x) * 4;
    if (i >= n) return;
    float4 f = {v, v, v, v};
    *(float4*)&out[i] = f;
}

extern "C" void kernel_launch(void* const* d_in, const int* in_sizes, int n_in,
                              void* d_out, int out_size, void* d_ws, size_t ws_size,
                              hipStream_t stream) {
    dim3 blk(256);
    const int M = BATCH * S;  // 4096
    const int fill_blocks = (out_size / 4 + 255) / 256;

    int base = n_in - 18;
    bool layout_ok = (base >= 2) && (out_size == M * D) &&
                     (in_sizes[0] == M * D) && (in_sizes[1] == M * D) &&
                     (in_sizes[base] == L * D * D) && (in_sizes[base + 4] == L * D) &&
                     (in_sizes[base + 12] == L * D * DFF) && (in_sizes[base + 13] == L * DFF);
    if (!layout_ok) {
        fill_f32<<<fill_blocks, blk, 0, stream>>>((float*)d_out, 9000.f, out_size);
        return;
    }
    const float* x_in = (const float*)d_in[0];
    const float* enc  = (const float*)d_in[1];
    const float* Wq1 = (const float*)d_in[base + 0];
    const float* Wk1 = (const float*)d_in[base + 1];
    const float* Wv1 = (const float*)d_in[base + 2];
    const float* Wo1 = (const float*)d_in[base + 3];
    const float* g1  = (const float*)d_in[base + 4];
    const float* b1  = (const float*)d_in[base + 5];
    const float* Wq2 = (const float*)d_in[base + 6];
    const float* Wk2 = (const float*)d_in[base + 7];
    const float* Wv2 = (const float*)d_in[base + 8];
    const float* Wo2 = (const float*)d_in[base + 9];
    const float* g2  = (const float*)d_in[base + 10];
    const float* b2  = (const float*)d_in[base + 11];
    const float* Wf1 = (const float*)d_in[base + 12];
    const float* bf1 = (const float*)d_in[base + 13];
    const float* Wf2 = (const float*)d_in[base + 14];
    const float* bf2 = (const float*)d_in[base + 15];
    const float* g3  = (const float*)d_in[base + 16];
    const float* b3  = (const float*)d_in[base + 17];

    const size_t PL = (size_t)M * D * 2;   // 8 MiB bf16 plane
    const size_t WB = (size_t)D * D * 2;   // 2 MiB weight plane
    const size_t required = 22 * PL;       // 176 MiB
    if (ws_size < required) {
        fill_f32<<<fill_blocks, blk, 0, stream>>>((float*)d_out, 500.f, out_size);
        return;
    }

    char* ws = (char*)d_ws;
    size_t off = 0;
    auto carve = [&](size_t bytes) -> char* {
        char* p = ws + off;
        off += (bytes + 255) & ~(size_t)255;
        return p;
    };
    float*  xf = (float*)carve(2 * PL);
    ushort* xh = (ushort*)carve(PL);     // xh,eh adjacent; xl,el adjacent (z=2 cross)
    ushort* eh = (ushort*)carve(PL);
    ushort* xl = (ushort*)carve(PL);
    ushort* el = (ushort*)carve(PL);
    char*   clu = carve(10 * PL);        // 80 MiB scratch
    ushort* uvh = (ushort*)clu;                  // u|vo [M][2048] hi (16MB)
    ushort* uvl = (ushort*)(clu + 2 * PL);       // lo (16MB)
    ushort* vth = (ushort*)(clu + 4 * PL);       // vo^T [b][d][s] (8MB)
    ushort* vtl = (ushort*)(clu + 5 * PL);
    float*  scores = (float*)(clu + 6 * PL);     // 16MB
    ushort* Astkh = (ushort*)(clu + 6 * PL);     // weight-prep aliases
    ushort* Astkl = (ushort*)(clu + 7 * PL);
    ushort* Bstkh = (ushort*)(clu + 8 * PL);
    ushort* Bstkl = (ushort*)(clu + 9 * PL);
    float*  wpart = (float*)clu;                 // FFN: 32MB partials
    ushort* wf2Th = (ushort*)(clu + 4 * PL);
    ushort* wf2Tl = (ushort*)(clu + 5 * PL);
    ushort* wpH   = (ushort*)(clu + 6 * PL);
    ushort* wpL   = (ushort*)(clu + 6 * PL + WB);
    float*  bprime = (float*)(clu + 6 * PL + 2 * WB);
    ushort* ph = (ushort*)carve(PL);
    ushort* pl_ = (ushort*)carve(PL);
    float*  yf = (float*)carve(2 * PL);
    ushort* WTh = (ushort*)carve(PL);    // [4][D][D]: WqkT1, WvoT1, WqkT2, WvoT2
    ushort* WTl = (ushort*)carve(PL);

    auto gemm = [&](const ushort* Ah, const ushort* Al, const ushort* Bh, const ushort* Bl,
                    float* Cf, ushort* Ch, ushort* Cl, const float* bias, float alpha,
                    int gm, int gn, int gk, int lda, int ldb, int ldc,
                    long sA, long sB, long sC, int batch, int tri) {
        dim3 g(gn / 128, gm / 128, batch);
        gemm3<<<g, blk, 0, stream>>>(Ah, Al, Bh, Bl, Cf, Ch, Cl, bias, alpha,
                                     gm, gn, gk, lda, ldb, ldc, sA, sB, sC, tri);
    };
    auto cvtw = [&](const float* W, ushort* oh, ushort* ol) {
        cvt_split<<<(D * D) / 1024, blk, 0, stream>>>(W, oh, ol, D * D);
    };

    cvt_split<<<(M * D) / 1024, blk, 0, stream>>>(x_in, xh, xl, M * D);
    cvt_split<<<(M * D) / 1024, blk, 0, stream>>>(enc, eh, el, M * D);

    const long SM = (long)S * S;
    const long SD = (long)S * D;
    const long DD = (long)D * D;

    for (int i = 0; i < L; i++) {
        size_t wo = (size_t)i * D * D;
        // ===== weight prep: WqkT = Wk@Wq^T ; WvoT = Wo^T@Wv^T (batched z=4) =====
        cvtw(Wk1 + wo, Astkh + 0 * DD, Astkl + 0 * DD);
        transpose_w<<<dim3(D / 32, D / 32), blk, 0, stream>>>(Wo1 + wo, Astkh + 1 * DD, Astkl + 1 * DD, D, D);
        cvtw(Wk2 + wo, Astkh + 2 * DD, Astkl + 2 * DD);
        transpose_w<<<dim3(D / 32, D / 32), blk, 0, stream>>>(Wo2 + wo, Astkh + 3 * DD, Astkl + 3 * DD, D, D);
        cvtw(Wq1 + wo, Bstkh + 0 * DD, Bstkl + 0 * DD);
        cvtw(Wv1 + wo, Bstkh + 1 * DD, Bstkl + 1 * DD);
        cvtw(Wq2 + wo, Bstkh + 2 * DD, Bstkl + 2 * DD);
        cvtw(Wv2 + wo, Bstkh + 3 * DD, Bstkl + 3 * DD);
        gemm(Astkh, Astkl, Bstkh, Bstkl, nullptr, WTh, WTl, nullptr, 1.f,
             D, D, D, D, D, D, DD, DD, DD, 4, 0);

        // ===== self-attention (causal) =====
        gemm(xh, xl, WTh, WTl, nullptr, uvh, uvl, nullptr, 1.f,
             M, 2 * D, D, D, D, 2 * D, 0, 0, 0, 1, 0);
        vtrans<<<dim3(D / 32, S / 32, 2 * BATCH), blk, 0, stream>>>(uvh, uvl, vth, vtl, 2 * D, D);
        gemm(uvh, uvl, xh, xl, scores, nullptr, nullptr, nullptr, 0.125f,
             S, S, D, 2 * D, D, S, (long)S * 2 * D, SD, SM, BATCH, 1);
        softmax_rows<<<dim3(S, BATCH), blk, 0, stream>>>(scores, ph, pl_, 1);
        gemm(ph, pl_, vth, vtl, yf, nullptr, nullptr, nullptr, 1.f,
             S, D, S, S, S, D, SM, SD, SD, BATCH, 2);
        ln_res<<<M, blk, 0, stream>>>((i == 0) ? x_in : xf, yf,
                                      g1 + (size_t)i * D, b1 + (size_t)i * D, xf, xh, xl);

        // ===== cross-attention =====
        gemm(xh, xl, WTh + 2 * DD, WTl + 2 * DD, nullptr, uvh, uvl, nullptr, 1.f,
             M, D, D, D, D, 2 * D, (long)M * D, DD, D, 2, 0);
        vtrans<<<dim3(D / 32, S / 32, 2 * BATCH), blk, 0, stream>>>(uvh, uvl, vth, vtl, 2 * D, D);
        gemm(uvh, uvl, eh, el, scores, nullptr, nullptr, nullptr, 0.125f,
             S, S, D, 2 * D, D, S, (long)S * 2 * D, SD, SM, BATCH, 0);
        softmax_rows<<<dim3(S, BATCH), blk, 0, stream>>>(scores, ph, pl_, 0);
        gemm(ph, pl_, vth, vtl, yf, nullptr, nullptr, nullptr, 1.f,
             S, D, S, S, S, D, SM, SD, SD, BATCH, 0);
        ln_res<<<M, blk, 0, stream>>>(xf, yf, g2 + (size_t)i * D, b2 + (size_t)i * D, xf, xh, xl);

        // ===== feedforward (collapsed) =====
        const float* Wf1i = Wf1 + (size_t)i * D * DFF;
        const float* Wf2i = Wf2 + (size_t)i * DFF * D;
        transpose_w<<<dim3(D / 32, DFF / 32), blk, 0, stream>>>(Wf2i, wf2Th, wf2Tl, DFF, D);
        cvt_split<<<(D * DFF) / 1024, blk, 0, stream>>>(Wf1i, ph, pl_, D * DFF);
        gemm(wf2Th, wf2Tl, ph, pl_, wpart, nullptr, nullptr, nullptr, 1.f,
             1024, 1024, 512, DFF, DFF, 1024, 512, 512, 1048576, 8, 0);
        reduce_split<<<1024, blk, 0, stream>>>(wpart, wpH, wpL);
        bias_fold<<<16, blk, 0, stream>>>(bf1 + (size_t)i * DFF, Wf2i,
                                          bf2 + (size_t)i * D, bprime);
        gemm(xh, xl, wpH, wpL, yf, nullptr, nullptr, bprime, 1.f,
             M, D, D, D, D, D, 0, 0, 0, 1, 0);
        ln_res<<<M, blk, 0, stream>>>(xf, yf, g3 + (size_t)i * D, b3 + (size_t)i * D,
                                      (i == L - 1) ? (float*)d_out : xf, xh, xl);
    }
}

// Round 18
// 2999.638 us; speedup vs baseline: 2.2684x; 2.2684x over previous
//
#include <hip/hip_runtime.h>

#define L 6
#define D 1024
#define DFF 4096
#define BATCH 4
#define S 1024

typedef __attribute__((ext_vector_type(4))) float f32x4;
typedef __attribute__((ext_vector_type(8))) short short8;

__device__ __forceinline__ ushort f2bf(float f) {
    unsigned int u = __float_as_uint(f);
    u = u + 0x7FFF + ((u >> 16) & 1);
    return (ushort)(u >> 16);
}
__device__ __forceinline__ float bf2f(ushort u) {
    return __uint_as_float(((unsigned int)u) << 16);
}
__device__ __forceinline__ void gload16(const ushort* g, ushort* l) {
    __builtin_amdgcn_global_load_lds(
        (const __attribute__((address_space(1))) void*)g,
        (__attribute__((address_space(3))) void*)l, 16, 0, 0);
}

// ---------------- split f32 -> (hi, lo) bf16 planes ----------------
__global__ __launch_bounds__(256) void cvt_split(const float* __restrict__ in,
                                                 ushort* __restrict__ oh,
                                                 ushort* __restrict__ ol, int n) {
    int i = (blockIdx.x * 256 + threadIdx.x) * 4;
    if (i >= n) return;
    float4 v = *(const float4*)&in[i];
    ushort4 h, l;
    h.x = f2bf(v.x); l.x = f2bf(v.x - bf2f(h.x));
    h.y = f2bf(v.y); l.y = f2bf(v.y - bf2f(h.y));
    h.z = f2bf(v.z); l.z = f2bf(v.z - bf2f(h.z));
    h.w = f2bf(v.w); l.w = f2bf(v.w - bf2f(h.w));
    *(ushort4*)&oh[i] = h;
    *(ushort4*)&ol[i] = l;
}

// ------- transpose weight [K,N] f32 -> [N,K] h/l bf16 -------
__global__ __launch_bounds__(256) void transpose_w(const float* __restrict__ W,
                                                   ushort* __restrict__ outh,
                                                   ushort* __restrict__ outl,
                                                   int K, int N) {
    __shared__ float T[32][33];
    int n0 = blockIdx.x * 32, k0 = blockIdx.y * 32;
    int t = threadIdx.x;
    int r = t >> 3, c4 = (t & 7) * 4;
    float4 v = *(const float4*)&W[(size_t)(k0 + r) * N + n0 + c4];
    T[r][c4 + 0] = v.x; T[r][c4 + 1] = v.y; T[r][c4 + 2] = v.z; T[r][c4 + 3] = v.w;
    __syncthreads();
    float a0 = T[c4 + 0][r], a1 = T[c4 + 1][r], a2 = T[c4 + 2][r], a3 = T[c4 + 3][r];
    ushort4 h, l;
    h.x = f2bf(a0); l.x = f2bf(a0 - bf2f(h.x));
    h.y = f2bf(a1); l.y = f2bf(a1 - bf2f(h.y));
    h.z = f2bf(a2); l.z = f2bf(a2 - bf2f(h.z));
    h.w = f2bf(a3); l.w = f2bf(a3 - bf2f(h.w));
    size_t ob = (size_t)(n0 + r) * K + k0 + c4;
    *(ushort4*)&outh[ob] = h;
    *(ushort4*)&outl[ob] = l;
}

// ---------------- transpose vo planes [b][s][2048-strided] -> [b][d][s] ----------------
__global__ __launch_bounds__(256) void vtrans(const ushort* __restrict__ inh,
                                              const ushort* __restrict__ inl,
                                              ushort* __restrict__ outh,
                                              ushort* __restrict__ outl,
                                              int ld_in, int col_off) {
    __shared__ ushort T[32][40];
    const int pz = blockIdx.z, b = pz >> 1;
    const ushort* in = (pz & 1) ? inl : inh;
    ushort* out = (pz & 1) ? outl : outh;
    const int d0 = blockIdx.x * 32, s0 = blockIdx.y * 32;
    const int t = threadIdx.x, r = t >> 3, c4 = (t & 7) * 4;
    ushort4 v = *(const ushort4*)&in[(size_t)(b * S + s0 + r) * ld_in + col_off + d0 + c4];
    T[r][c4 + 0] = v.x; T[r][c4 + 1] = v.y; T[r][c4 + 2] = v.z; T[r][c4 + 3] = v.w;
    __syncthreads();
    ushort4 o = {T[c4 + 0][r], T[c4 + 1][r], T[c4 + 2][r], T[c4 + 3][r]};
    *(ushort4*)&out[(size_t)(b * D + d0 + r) * S + s0 + c4] = o;
}

// -------- reduce 8 split-K f32 partials [8][1024][1024] -> h/l bf16 planes --------
__global__ __launch_bounds__(256) void reduce_split(const float* __restrict__ part,
                                                    ushort* __restrict__ oh,
                                                    ushort* __restrict__ ol) {
    int i = (blockIdx.x * 256 + threadIdx.x) * 4;
    float4 s = *(const float4*)&part[i];
#pragma unroll
    for (int z = 1; z < 8; z++) {
        float4 p = *(const float4*)&part[(size_t)z * 1048576 + i];
        s.x += p.x; s.y += p.y; s.z += p.z; s.w += p.w;
    }
    ushort4 h, l;
    h.x = f2bf(s.x); l.x = f2bf(s.x - bf2f(h.x));
    h.y = f2bf(s.y); l.y = f2bf(s.y - bf2f(h.y));
    h.z = f2bf(s.z); l.z = f2bf(s.z - bf2f(h.z));
    h.w = f2bf(s.w); l.w = f2bf(s.w - bf2f(h.w));
    *(ushort4*)&oh[i] = h;
    *(ushort4*)&ol[i] = l;
}

// -------- bias fold: out[n] = sum_j bf1[j] * Wf2[j][n] + bf2[n] --------
__global__ __launch_bounds__(256) void bias_fold(const float* __restrict__ bf1,
                                                 const float* __restrict__ Wf2,
                                                 const float* __restrict__ bf2,
                                                 float* __restrict__ out) {
    __shared__ float red[4][64];
    const int lane = threadIdx.x & 63, js = threadIdx.x >> 6;
    const int n = blockIdx.x * 64 + lane;
    float s = 0.f;
    const int j0 = js * 1024;
    for (int j = j0; j < j0 + 1024; j++) s += bf1[j] * Wf2[(size_t)j * D + n];
    red[js][lane] = s;
    __syncthreads();
    if (js == 0) out[n] = red[0][lane] + red[1][lane] + red[2][lane] + red[3][lane] + bf2[n];
}

// ---------------- gemm3: 128x128 split-precision GEMM (proven) ----------------
// triMode: 0 none; 1 = causal scores (skip bx>by); 2 = causal PV (cap K-tiles)
__global__ __launch_bounds__(256) void gemm3(
    const ushort* __restrict__ Ah, const ushort* __restrict__ Al,
    const ushort* __restrict__ Bh, const ushort* __restrict__ Bl,
    float* __restrict__ Cf, ushort* __restrict__ Ch, ushort* __restrict__ Cl,
    const float* __restrict__ bias, float alpha,
    int M, int N, int K, int lda, int ldb, int ldc,
    long sA, long sB, long sC, int triMode) {
    __shared__ ushort lds[4 * 128 * 64];
    ushort* Ash = lds;
    ushort* Asl = lds + 128 * 64;
    ushort* Bsh = lds + 2 * 128 * 64;
    ushort* Bsl = lds + 3 * 128 * 64;

    const int gx = gridDim.x, gy = gridDim.y;
    int nblk = gx * gy * gridDim.z;
    int bid = (blockIdx.z * gy + blockIdx.y) * gx + blockIdx.x;
    if ((nblk & 7) == 0) bid = (bid & 7) * (nblk >> 3) + (bid >> 3);
    const int bx = bid % gx;
    int rem = bid / gx;
    const int by = rem % gy;
    const int z = rem / gy;

    if (triMode == 1 && bx > by) return;
    int NT = K >> 6;
    if (triMode == 2) {
        int cap = 2 * by + 2;
        if (cap < NT) NT = cap;
    }

    const int bm = by * 128, bn = bx * 128;
    const ushort* A0 = Ah + (size_t)z * sA;
    const ushort* A1 = Al + (size_t)z * sA;
    const ushort* B0 = Bh + (size_t)z * sB;
    const ushort* B1 = Bl + (size_t)z * sB;
    const size_t coff = (size_t)z * sC;

    const int tid = threadIdx.x, lane = tid & 63;
    const int wid = tid >> 6, wr = wid >> 1, wc = wid & 1;
    const int lr = lane & 15, lg = lane >> 4;

    f32x4 acc[4][4] = {};

    for (int kt = 0; kt < NT; kt++) {
        const int k0 = kt << 6;
        if (kt) __syncthreads();
#pragma unroll
        for (int c = 0; c < 4; c++) {
            const int idx = c * 256 + tid;
            const int row = idx >> 3;
            const int col = (((idx & 7) ^ (row & 7)) * 8);
            const int lbase = (c * 256 + (tid & 192)) * 8;
            const size_t aoff = (size_t)(bm + row) * lda + k0 + col;
            const size_t boff = (size_t)(bn + row) * ldb + k0 + col;
            gload16(A0 + aoff, Ash + lbase);
            gload16(A1 + aoff, Asl + lbase);
            gload16(B0 + boff, Bsh + lbase);
            gload16(B1 + boff, Bsl + lbase);
        }
        asm volatile("s_waitcnt vmcnt(0)" ::: "memory");
        __syncthreads();
#pragma unroll
        for (int ks = 0; ks < 2; ks++) {
            short8 afh[4], afl[4], bfh[4], bfl[4];
#pragma unroll
            for (int i = 0; i < 4; i++) {
                const int arow = wr * 64 + i * 16 + lr;
                const int brow = wc * 64 + i * 16 + lr;
                const int ar = arow * 64 + ((ks * 4 + lg) ^ (arow & 7)) * 8;
                const int br = brow * 64 + ((ks * 4 + lg) ^ (brow & 7)) * 8;
                afh[i] = *(const short8*)&Ash[ar];
                afl[i] = *(const short8*)&Asl[ar];
                bfh[i] = *(const short8*)&Bsh[br];
                bfl[i] = *(const short8*)&Bsl[br];
            }
#pragma unroll
            for (int i = 0; i < 4; i++)
#pragma unroll
                for (int j = 0; j < 4; j++) {
                    acc[i][j] = __builtin_amdgcn_mfma_f32_16x16x32_bf16(afh[i], bfh[j], acc[i][j], 0, 0, 0);
                    acc[i][j] = __builtin_amdgcn_mfma_f32_16x16x32_bf16(afh[i], bfl[j], acc[i][j], 0, 0, 0);
                    acc[i][j] = __builtin_amdgcn_mfma_f32_16x16x32_bf16(afl[i], bfh[j], acc[i][j], 0, 0, 0);
                }
        }
    }
#pragma unroll
    for (int j = 0; j < 4; j++) {
        const int n = bn + wc * 64 + j * 16 + lr;
        const float bv = bias ? bias[n] : 0.f;
#pragma unroll
        for (int i = 0; i < 4; i++) {
#pragma unroll
            for (int r = 0; r < 4; r++) {
                const int m = bm + wr * 64 + i * 16 + lg * 4 + r;
                float v = acc[i][j][r] * alpha + bv;
                const size_t ci = coff + (size_t)m * ldc + n;
                if (Cf) Cf[ci] = v;
                if (Ch) {
                    ushort h = f2bf(v);
                    Ch[ci] = h;
                    Cl[ci] = f2bf(v - bf2f(h));
                }
            }
        }
    }
}

// ---------------- row softmax (f32 in, h/l bf16 planes out) ----------------
__global__ __launch_bounds__(256) void softmax_rows(const float* __restrict__ Sc,
                                                    ushort* __restrict__ Ph,
                                                    ushort* __restrict__ Pl, int causal) {
    __shared__ float red[4];
    int q = blockIdx.x, b = blockIdx.y;
    size_t base = ((size_t)b * S + q) * S;
    int valid = causal ? (q + 1) : S;
    int tid = threadIdx.x;
    float v[4];
    float mx = -3e38f;
#pragma unroll
    for (int j = 0; j < 4; j++) {
        int c = tid + j * 256;
        float x = (c < valid) ? Sc[base + c] : -3e38f;
        v[j] = x;
        mx = fmaxf(mx, v[j]);
    }
    for (int o = 32; o; o >>= 1) mx = fmaxf(mx, __shfl_xor(mx, o));
    if ((tid & 63) == 0) red[tid >> 6] = mx;
    __syncthreads();
    mx = fmaxf(fmaxf(red[0], red[1]), fmaxf(red[2], red[3]));
    float s = 0.f;
#pragma unroll
    for (int j = 0; j < 4; j++) {
        int c = tid + j * 256;
        float e = (c < valid) ? __expf(v[j] - mx) : 0.f;
        v[j] = e;
        s += e;
    }
    for (int o = 32; o; o >>= 1) s += __shfl_xor(s, o);
    __syncthreads();
    if ((tid & 63) == 0) red[tid >> 6] = s;
    __syncthreads();
    s = red[0] + red[1] + red[2] + red[3];
    float inv = 1.0f / s;
#pragma unroll
    for (int j = 0; j < 4; j++) {
        int c = tid + j * 256;
        float p = v[j] * inv;
        ushort h = f2bf(p);
        Ph[base + c] = h;
        Pl[base + c] = f2bf(p - bf2f(h));
    }
}

// ---------------- residual + layernorm (f32 in, f32 + h/l planes out) ----------------
__global__ __launch_bounds__(256) void ln_res(const float* __restrict__ xin,
                                              const float* __restrict__ y,
                                              const float* __restrict__ g,
                                              const float* __restrict__ bta,
                                              float* __restrict__ xof,
                                              ushort* __restrict__ xh,
                                              ushort* __restrict__ xl) {
    __shared__ float red[4];
    int row = blockIdx.x;
    size_t base = (size_t)row * D;
    int tid = threadIdx.x;
    int c0 = tid * 4;
    float4 xv = *(const float4*)&xin[base + c0];
    float4 yv = *(const float4*)&y[base + c0];
    float t[4] = {xv.x + yv.x, xv.y + yv.y, xv.z + yv.z, xv.w + yv.w};
    float s = t[0] + t[1] + t[2] + t[3];
    for (int o = 32; o; o >>= 1) s += __shfl_xor(s, o);
    if ((tid & 63) == 0) red[tid >> 6] = s;
    __syncthreads();
    s = red[0] + red[1] + red[2] + red[3];
    float mean = s * (1.0f / D);
    float vs = 0.f;
#pragma unroll
    for (int j = 0; j < 4; j++) {
        float dd = t[j] - mean;
        vs += dd * dd;
    }
    for (int o = 32; o; o >>= 1) vs += __shfl_xor(vs, o);
    __syncthreads();
    if ((tid & 63) == 0) red[tid >> 6] = vs;
    __syncthreads();
    vs = red[0] + red[1] + red[2] + red[3];
    float inv = rsqrtf(vs * (1.0f / D) + 1e-5f);
    float4 gv = *(const float4*)&g[c0];
    float4 bv = *(const float4*)&bta[c0];
    float o0 = (t[0] - mean) * inv * gv.x + bv.x;
    float o1 = (t[1] - mean) * inv * gv.y + bv.y;
    float o2 = (t[2] - mean) * inv * gv.z + bv.z;
    float o3 = (t[3] - mean) * inv * gv.w + bv.w;
    float4 fo = {o0, o1, o2, o3};
    *(float4*)&xof[base + c0] = fo;
    ushort4 h, l;
    h.x = f2bf(o0); l.x = f2bf(o0 - bf2f(h.x));
    h.y = f2bf(o1); l.y = f2bf(o1 - bf2f(h.y));
    h.z = f2bf(o2); l.z = f2bf(o2 - bf2f(h.z));
    h.w = f2bf(o3); l.w = f2bf(o3 - bf2f(h.w));
    *(ushort4*)&xh[base + c0] = h;
    *(ushort4*)&xl[base + c0] = l;
}

__global__ __launch_bounds__(256) void fill_f32(float* out, float v, int n) {
    int i = (blockIdx.x * 256 + threadIdx.x) * 4;
    if (i >= n) return;
    float4 f = {v, v, v, v};
    *(float4*)&out[i] = f;
}

extern "C" void kernel_launch(void* const* d_in, const int* in_sizes, int n_in,
                              void* d_out, int out_size, void* d_ws, size_t ws_size,
                              hipStream_t stream) {
    dim3 blk(256);
    const int M = BATCH * S;  // 4096
    const int fill_blocks = (out_size / 4 + 255) / 256;

    int base = n_in - 18;
    bool layout_ok = (base >= 2) && (out_size == M * D) &&
                     (in_sizes[0] == M * D) && (in_sizes[1] == M * D) &&
                     (in_sizes[base] == L * D * D) && (in_sizes[base + 4] == L * D) &&
                     (in_sizes[base + 12] == L * D * DFF) && (in_sizes[base + 13] == L * DFF);
    if (!layout_ok) {
        fill_f32<<<fill_blocks, blk, 0, stream>>>((float*)d_out, 9000.f, out_size);
        return;
    }
    const float* x_in = (const float*)d_in[0];
    const float* enc  = (const float*)d_in[1];
    const float* Wq1 = (const float*)d_in[base + 0];
    const float* Wk1 = (const float*)d_in[base + 1];
    const float* Wv1 = (const float*)d_in[base + 2];
    const float* Wo1 = (const float*)d_in[base + 3];
    const float* g1  = (const float*)d_in[base + 4];
    const float* b1  = (const float*)d_in[base + 5];
    const float* Wq2 = (const float*)d_in[base + 6];
    const float* Wk2 = (const float*)d_in[base + 7];
    const float* Wv2 = (const float*)d_in[base + 8];
    const float* Wo2 = (const float*)d_in[base + 9];
    const float* g2  = (const float*)d_in[base + 10];
    const float* b2  = (const float*)d_in[base + 11];
    const float* Wf1 = (const float*)d_in[base + 12];
    const float* bf1 = (const float*)d_in[base + 13];
    const float* Wf2 = (const float*)d_in[base + 14];
    const float* bf2 = (const float*)d_in[base + 15];
    const float* g3  = (const float*)d_in[base + 16];
    const float* b3  = (const float*)d_in[base + 17];

    const size_t PL = (size_t)M * D * 2;   // 8 MiB bf16 plane
    const size_t WB = (size_t)D * D * 2;   // 2 MiB weight plane
    const size_t required = 22 * PL;       // 176 MiB
    if (ws_size < required) {
        fill_f32<<<fill_blocks, blk, 0, stream>>>((float*)d_out, 500.f, out_size);
        return;
    }

    char* ws = (char*)d_ws;
    size_t off = 0;
    auto carve = [&](size_t bytes) -> char* {
        char* p = ws + off;
        off += (bytes + 255) & ~(size_t)255;
        return p;
    };
    float*  xf = (float*)carve(2 * PL);
    ushort* xh = (ushort*)carve(PL);     // xh,eh adjacent; xl,el adjacent (z=2 cross)
    ushort* eh = (ushort*)carve(PL);
    ushort* xl = (ushort*)carve(PL);
    ushort* el = (ushort*)carve(PL);
    char*   clu = carve(10 * PL);        // 80 MiB scratch
    ushort* uvh = (ushort*)clu;                  // u|vo [M][2048] hi (16MB)
    ushort* uvl = (ushort*)(clu + 2 * PL);       // lo (16MB)
    ushort* vth = (ushort*)(clu + 4 * PL);       // vo^T [b][d][s] (8MB)
    ushort* vtl = (ushort*)(clu + 5 * PL);
    float*  scores = (float*)(clu + 6 * PL);     // 16MB
    ushort* Astkh = (ushort*)(clu + 6 * PL);     // weight-prep aliases
    ushort* Astkl = (ushort*)(clu + 7 * PL);
    ushort* Bstkh = (ushort*)(clu + 8 * PL);
    ushort* Bstkl = (ushort*)(clu + 9 * PL);
    float*  wpart = (float*)clu;                 // FFN: 32MB partials
    ushort* wf2Th = (ushort*)(clu + 4 * PL);
    ushort* wf2Tl = (ushort*)(clu + 5 * PL);
    ushort* wpH   = (ushort*)(clu + 6 * PL);
    ushort* wpL   = (ushort*)(clu + 6 * PL + WB);
    float*  bprime = (float*)(clu + 6 * PL + 2 * WB);
    ushort* ph = (ushort*)carve(PL);
    ushort* pl_ = (ushort*)carve(PL);
    float*  yf = (float*)carve(2 * PL);
    ushort* WTh = (ushort*)carve(PL);    // [4][D][D]: WqkT1, WvoT1, WqkT2, WvoT2
    ushort* WTl = (ushort*)carve(PL);

    auto gemm = [&](const ushort* Ah, const ushort* Al, const ushort* Bh, const ushort* Bl,
                    float* Cf, ushort* Ch, ushort* Cl, const float* bias, float alpha,
                    int gm, int gn, int gk, int lda, int ldb, int ldc,
                    long sA, long sB, long sC, int batch, int tri) {
        dim3 g(gn / 128, gm / 128, batch);
        gemm3<<<g, blk, 0, stream>>>(Ah, Al, Bh, Bl, Cf, Ch, Cl, bias, alpha,
                                     gm, gn, gk, lda, ldb, ldc, sA, sB, sC, tri);
    };
    auto cvtw = [&](const float* W, ushort* oh, ushort* ol) {
        cvt_split<<<(D * D) / 1024, blk, 0, stream>>>(W, oh, ol, D * D);
    };

    cvt_split<<<(M * D) / 1024, blk, 0, stream>>>(x_in, xh, xl, M * D);
    cvt_split<<<(M * D) / 1024, blk, 0, stream>>>(enc, eh, el, M * D);

    const long SM = (long)S * S;
    const long SD = (long)S * D;
    const long DD = (long)D * D;

    for (int i = 0; i < L; i++) {
        size_t wo = (size_t)i * D * D;
        // ===== weight prep: WqkT = Wk@Wq^T ; WvoT = Wo^T@Wv^T (batched z=4) =====
        cvtw(Wk1 + wo, Astkh + 0 * DD, Astkl + 0 * DD);
        transpose_w<<<dim3(D / 32, D / 32), blk, 0, stream>>>(Wo1 + wo, Astkh + 1 * DD, Astkl + 1 * DD, D, D);
        cvtw(Wk2 + wo, Astkh + 2 * DD, Astkl + 2 * DD);
        transpose_w<<<dim3(D / 32, D / 32), blk, 0, stream>>>(Wo2 + wo, Astkh + 3 * DD, Astkl + 3 * DD, D, D);
        cvtw(Wq1 + wo, Bstkh + 0 * DD, Bstkl + 0 * DD);
        cvtw(Wv1 + wo, Bstkh + 1 * DD, Bstkl + 1 * DD);
        cvtw(Wq2 + wo, Bstkh + 2 * DD, Bstkl + 2 * DD);
        cvtw(Wv2 + wo, Bstkh + 3 * DD, Bstkl + 3 * DD);
        gemm(Astkh, Astkl, Bstkh, Bstkl, nullptr, WTh, WTl, nullptr, 1.f,
             D, D, D, D, D, D, DD, DD, DD, 4, 0);

        // ===== self-attention (causal) =====
        gemm(xh, xl, WTh, WTl, nullptr, uvh, uvl, nullptr, 1.f,
             M, 2 * D, D, D, D, 2 * D, 0, 0, 0, 1, 0);
        vtrans<<<dim3(D / 32, S / 32, 2 * BATCH), blk, 0, stream>>>(uvh, uvl, vth, vtl, 2 * D, D);
        gemm(uvh, uvl, xh, xl, scores, nullptr, nullptr, nullptr, 0.125f,
             S, S, D, 2 * D, D, S, (long)S * 2 * D, SD, SM, BATCH, 1);
        softmax_rows<<<dim3(S, BATCH), blk, 0, stream>>>(scores, ph, pl_, 1);
        gemm(ph, pl_, vth, vtl, yf, nullptr, nullptr, nullptr, 1.f,
             S, D, S, S, S, D, SM, SD, SD, BATCH, 2);
        ln_res<<<M, blk, 0, stream>>>((i == 0) ? x_in : xf, yf,
                                      g1 + (size_t)i * D, b1 + (size_t)i * D, xf, xh, xl);

        // ===== cross-attention =====
        gemm(xh, xl, WTh + 2 * DD, WTl + 2 * DD, nullptr, uvh, uvl, nullptr, 1.f,
             M, D, D, D, D, 2 * D, (long)M * D, DD, D, 2, 0);
        vtrans<<<dim3(D / 32, S / 32, 2 * BATCH), blk, 0, stream>>>(uvh, uvl, vth, vtl, 2 * D, D);
        gemm(uvh, uvl, eh, el, scores, nullptr, nullptr, nullptr, 0.125f,
             S, S, D, 2 * D, D, S, (long)S * 2 * D, SD, SM, BATCH, 0);
        softmax_rows<<<dim3(S, BATCH), blk, 0, stream>>>(scores, ph, pl_, 0);
        gemm(ph, pl_, vth, vtl, yf, nullptr, nullptr, nullptr, 1.f,
             S, D, S, S, S, D, SM, SD, SD, BATCH, 0);
        ln_res<<<M, blk, 0, stream>>>(xf, yf, g2 + (size_t)i * D, b2 + (size_t)i * D, xf, xh, xl);

        // ===== feedforward (collapsed) =====
        const float* Wf1i = Wf1 + (size_t)i * D * DFF;
        const float* Wf2i = Wf2 + (size_t)i * DFF * D;
        transpose_w<<<dim3(D / 32, DFF / 32), blk, 0, stream>>>(Wf2i, wf2Th, wf2Tl, DFF, D);
        cvt_split<<<(D * DFF) / 1024, blk, 0, stream>>>(Wf1i, ph, pl_, D * DFF);
        gemm(wf2Th, wf2Tl, ph, pl_, wpart, nullptr, nullptr, nullptr, 1.f,
             1024, 1024, 512, DFF, DFF, 1024, 512, 512, 1048576, 8, 0);
        reduce_split<<<1024, blk, 0, stream>>>(wpart, wpH, wpL);
        bias_fold<<<16, blk, 0, stream>>>(bf1 + (size_t)i * DFF, Wf2i,
                                          bf2 + (size_t)i * D, bprime);
        gemm(xh, xl, wpH, wpL, yf, nullptr, nullptr, bprime, 1.f,
             M, D, D, D, D, D, 0, 0, 0, 1, 0);
        ln_res<<<M, blk, 0, stream>>>(xf, yf, g3 + (size_t)i * D, b3 + (size_t)i * D,
                                      (i == L - 1) ? (float*)d_out : xf, xh, xl);
    }
}

// Round 19
// 2849.245 us; speedup vs baseline: 2.3881x; 1.0528x over previous
//
#include <hip/hip_runtime.h>

#define L 6
#define D 1024
#define DFF 4096
#define BATCH 4
#define S 1024

typedef __attribute__((ext_vector_type(4))) float f32x4;
typedef __attribute__((ext_vector_type(8))) short short8;

__device__ __forceinline__ ushort f2bf(float f) {
    unsigned int u = __float_as_uint(f);
    u = u + 0x7FFF + ((u >> 16) & 1);
    return (ushort)(u >> 16);
}
__device__ __forceinline__ float bf2f(ushort u) {
    return __uint_as_float(((unsigned int)u) << 16);
}
__device__ __forceinline__ void gload16(const ushort* g, ushort* l) {
    __builtin_amdgcn_global_load_lds(
        (const __attribute__((address_space(1))) void*)g,
        (__attribute__((address_space(3))) void*)l, 16, 0, 0);
}

// ---------------- split f32 -> (hi, lo) bf16 planes ----------------
__global__ __launch_bounds__(256) void cvt_split(const float* __restrict__ in,
                                                 ushort* __restrict__ oh,
                                                 ushort* __restrict__ ol, int n) {
    int i = (blockIdx.x * 256 + threadIdx.x) * 4;
    if (i >= n) return;
    float4 v = *(const float4*)&in[i];
    ushort4 h, l;
    h.x = f2bf(v.x); l.x = f2bf(v.x - bf2f(h.x));
    h.y = f2bf(v.y); l.y = f2bf(v.y - bf2f(h.y));
    h.z = f2bf(v.z); l.z = f2bf(v.z - bf2f(h.z));
    h.w = f2bf(v.w); l.w = f2bf(v.w - bf2f(h.w));
    *(ushort4*)&oh[i] = h;
    *(ushort4*)&ol[i] = l;
}

// ------- transpose weight [K,N] f32 -> [N,K] h/l bf16 -------
__global__ __launch_bounds__(256) void transpose_w(const float* __restrict__ W,
                                                   ushort* __restrict__ outh,
                                                   ushort* __restrict__ outl,
                                                   int K, int N) {
    __shared__ float T[32][33];
    int n0 = blockIdx.x * 32, k0 = blockIdx.y * 32;
    int t = threadIdx.x;
    int r = t >> 3, c4 = (t & 7) * 4;
    float4 v = *(const float4*)&W[(size_t)(k0 + r) * N + n0 + c4];
    T[r][c4 + 0] = v.x; T[r][c4 + 1] = v.y; T[r][c4 + 2] = v.z; T[r][c4 + 3] = v.w;
    __syncthreads();
    float a0 = T[c4 + 0][r], a1 = T[c4 + 1][r], a2 = T[c4 + 2][r], a3 = T[c4 + 3][r];
    ushort4 h, l;
    h.x = f2bf(a0); l.x = f2bf(a0 - bf2f(h.x));
    h.y = f2bf(a1); l.y = f2bf(a1 - bf2f(h.y));
    h.z = f2bf(a2); l.z = f2bf(a2 - bf2f(h.z));
    h.w = f2bf(a3); l.w = f2bf(a3 - bf2f(h.w));
    size_t ob = (size_t)(n0 + r) * K + k0 + c4;
    *(ushort4*)&outh[ob] = h;
    *(ushort4*)&outl[ob] = l;
}

// ---------------- transpose vo planes [b][s][2048-strided] -> [b][d][s] ----------------
__global__ __launch_bounds__(256) void vtrans(const ushort* __restrict__ inh,
                                              const ushort* __restrict__ inl,
                                              ushort* __restrict__ outh,
                                              ushort* __restrict__ outl,
                                              int ld_in, int col_off) {
    __shared__ ushort T[32][40];
    const int pz = blockIdx.z, b = pz >> 1;
    const ushort* in = (pz & 1) ? inl : inh;
    ushort* out = (pz & 1) ? outl : outh;
    const int d0 = blockIdx.x * 32, s0 = blockIdx.y * 32;
    const int t = threadIdx.x, r = t >> 3, c4 = (t & 7) * 4;
    ushort4 v = *(const ushort4*)&in[(size_t)(b * S + s0 + r) * ld_in + col_off + d0 + c4];
    T[r][c4 + 0] = v.x; T[r][c4 + 1] = v.y; T[r][c4 + 2] = v.z; T[r][c4 + 3] = v.w;
    __syncthreads();
    ushort4 o = {T[c4 + 0][r], T[c4 + 1][r], T[c4 + 2][r], T[c4 + 3][r]};
    *(ushort4*)&out[(size_t)(b * D + d0 + r) * S + s0 + c4] = o;
}

// -------- reduce 8 split-K f32 partials [8][1024][1024] -> h/l bf16 planes --------
__global__ __launch_bounds__(256) void reduce_split(const float* __restrict__ part,
                                                    ushort* __restrict__ oh,
                                                    ushort* __restrict__ ol) {
    int i = (blockIdx.x * 256 + threadIdx.x) * 4;
    float4 s = *(const float4*)&part[i];
#pragma unroll
    for (int z = 1; z < 8; z++) {
        float4 p = *(const float4*)&part[(size_t)z * 1048576 + i];
        s.x += p.x; s.y += p.y; s.z += p.z; s.w += p.w;
    }
    ushort4 h, l;
    h.x = f2bf(s.x); l.x = f2bf(s.x - bf2f(h.x));
    h.y = f2bf(s.y); l.y = f2bf(s.y - bf2f(h.y));
    h.z = f2bf(s.z); l.z = f2bf(s.z - bf2f(h.z));
    h.w = f2bf(s.w); l.w = f2bf(s.w - bf2f(h.w));
    *(ushort4*)&oh[i] = h;
    *(ushort4*)&ol[i] = l;
}

// -------- bias fold: out[n] = sum_j bf1[j] * Wf2[j][n] + bf2[n] --------
__global__ __launch_bounds__(256) void bias_fold(const float* __restrict__ bf1,
                                                 const float* __restrict__ Wf2,
                                                 const float* __restrict__ bf2,
                                                 float* __restrict__ out) {
    __shared__ float red[4][64];
    const int lane = threadIdx.x & 63, js = threadIdx.x >> 6;
    const int n = blockIdx.x * 64 + lane;
    float s = 0.f;
    const int j0 = js * 1024;
    for (int j = j0; j < j0 + 1024; j++) s += bf1[j] * Wf2[(size_t)j * D + n];
    red[js][lane] = s;
    __syncthreads();
    if (js == 0) out[n] = red[0][lane] + red[1][lane] + red[2][lane] + red[3][lane] + bf2[n];
}

// ---------------- gemm3: 128x128 split-precision GEMM (proven K-loop) ----------------
// bf16 output path now stages C in LDS and writes back fully coalesced.
// triMode: 0 none; 1 = causal scores (skip bx>by); 2 = causal PV (cap K-tiles)
__global__ __launch_bounds__(256) void gemm3(
    const ushort* __restrict__ Ah, const ushort* __restrict__ Al,
    const ushort* __restrict__ Bh, const ushort* __restrict__ Bl,
    float* __restrict__ Cf, ushort* __restrict__ Ch, ushort* __restrict__ Cl,
    const float* __restrict__ bias, float alpha,
    int M, int N, int K, int lda, int ldb, int ldc,
    long sA, long sB, long sC, int triMode) {
    __shared__ ushort lds[4 * 128 * 64];   // 64 KiB (staging; reused for C-tile)
    ushort* Ash = lds;
    ushort* Asl = lds + 128 * 64;
    ushort* Bsh = lds + 2 * 128 * 64;
    ushort* Bsl = lds + 3 * 128 * 64;

    const int gx = gridDim.x, gy = gridDim.y;
    int nblk = gx * gy * gridDim.z;
    int bid = (blockIdx.z * gy + blockIdx.y) * gx + blockIdx.x;
    if ((nblk & 7) == 0) bid = (bid & 7) * (nblk >> 3) + (bid >> 3);
    const int bx = bid % gx;
    int rem = bid / gx;
    const int by = rem % gy;
    const int z = rem / gy;

    if (triMode == 1 && bx > by) return;
    int NT = K >> 6;
    if (triMode == 2) {
        int cap = 2 * by + 2;
        if (cap < NT) NT = cap;
    }

    const int bm = by * 128, bn = bx * 128;
    const ushort* A0 = Ah + (size_t)z * sA;
    const ushort* A1 = Al + (size_t)z * sA;
    const ushort* B0 = Bh + (size_t)z * sB;
    const ushort* B1 = Bl + (size_t)z * sB;
    const size_t coff = (size_t)z * sC;

    const int tid = threadIdx.x, lane = tid & 63;
    const int wid = tid >> 6, wr = wid >> 1, wc = wid & 1;
    const int lr = lane & 15, lg = lane >> 4;

    f32x4 acc[4][4] = {};

    for (int kt = 0; kt < NT; kt++) {
        const int k0 = kt << 6;
        if (kt) __syncthreads();
#pragma unroll
        for (int c = 0; c < 4; c++) {
            const int idx = c * 256 + tid;
            const int row = idx >> 3;
            const int col = (((idx & 7) ^ (row & 7)) * 8);
            const int lbase = (c * 256 + (tid & 192)) * 8;
            const size_t aoff = (size_t)(bm + row) * lda + k0 + col;
            const size_t boff = (size_t)(bn + row) * ldb + k0 + col;
            gload16(A0 + aoff, Ash + lbase);
            gload16(A1 + aoff, Asl + lbase);
            gload16(B0 + boff, Bsh + lbase);
            gload16(B1 + boff, Bsl + lbase);
        }
        asm volatile("s_waitcnt vmcnt(0)" ::: "memory");
        __syncthreads();
#pragma unroll
        for (int ks = 0; ks < 2; ks++) {
            short8 afh[4], afl[4], bfh[4], bfl[4];
#pragma unroll
            for (int i = 0; i < 4; i++) {
                const int arow = wr * 64 + i * 16 + lr;
                const int brow = wc * 64 + i * 16 + lr;
                const int ar = arow * 64 + ((ks * 4 + lg) ^ (arow & 7)) * 8;
                const int br = brow * 64 + ((ks * 4 + lg) ^ (brow & 7)) * 8;
                afh[i] = *(const short8*)&Ash[ar];
                afl[i] = *(const short8*)&Asl[ar];
                bfh[i] = *(const short8*)&Bsh[br];
                bfl[i] = *(const short8*)&Bsl[br];
            }
#pragma unroll
            for (int i = 0; i < 4; i++)
#pragma unroll
                for (int j = 0; j < 4; j++) {
                    acc[i][j] = __builtin_amdgcn_mfma_f32_16x16x32_bf16(afh[i], bfh[j], acc[i][j], 0, 0, 0);
                    acc[i][j] = __builtin_amdgcn_mfma_f32_16x16x32_bf16(afh[i], bfl[j], acc[i][j], 0, 0, 0);
                    acc[i][j] = __builtin_amdgcn_mfma_f32_16x16x32_bf16(afl[i], bfh[j], acc[i][j], 0, 0, 0);
                }
        }
    }
    if (Ch) {
        // stage packed (h|l) C-tile in LDS, then coalesced writeback
        __syncthreads();                     // all waves done reading staging LDS
        uint* lds32 = (uint*)lds;            // [128][128] u32 = 64 KiB
#pragma unroll
        for (int j = 0; j < 4; j++) {
            const int n = wc * 64 + j * 16 + lr;
            const float bv = bias ? bias[bn + n] : 0.f;
#pragma unroll
            for (int i = 0; i < 4; i++) {
#pragma unroll
                for (int r = 0; r < 4; r++) {
                    const int m = wr * 64 + i * 16 + lg * 4 + r;
                    float v = acc[i][j][r] * alpha + bv;
                    ushort h = f2bf(v);
                    ushort l2 = f2bf(v - bf2f(h));
                    lds32[m * 128 + n] = (uint)h | ((uint)l2 << 16);
                }
            }
        }
        __syncthreads();
#pragma unroll
        for (int it = 0; it < 16; it++) {
            const int flat = it * 1024 + tid * 4;   // u32 index in [128][128]
            const int row = flat >> 7, colc = flat & 127;
            uint4 p = *(const uint4*)&lds32[flat];
            ushort4 hh, ll;
            hh.x = (ushort)p.x; ll.x = (ushort)(p.x >> 16);
            hh.y = (ushort)p.y; ll.y = (ushort)(p.y >> 16);
            hh.z = (ushort)p.z; ll.z = (ushort)(p.z >> 16);
            hh.w = (ushort)p.w; ll.w = (ushort)(p.w >> 16);
            const size_t cio = coff + (size_t)(bm + row) * ldc + bn + colc;
            *(ushort4*)&Ch[cio] = hh;
            *(ushort4*)&Cl[cio] = ll;
        }
    } else {
#pragma unroll
        for (int j = 0; j < 4; j++) {
            const int n = bn + wc * 64 + j * 16 + lr;
            const float bv = bias ? bias[n] : 0.f;
#pragma unroll
            for (int i = 0; i < 4; i++) {
#pragma unroll
                for (int r = 0; r < 4; r++) {
                    const int m = bm + wr * 64 + i * 16 + lg * 4 + r;
                    Cf[coff + (size_t)m * ldc + n] = acc[i][j][r] * alpha + bv;
                }
            }
        }
    }
}

// ---------------- row softmax (f32 in, h/l bf16 planes out) ----------------
__global__ __launch_bounds__(256) void softmax_rows(const float* __restrict__ Sc,
                                                    ushort* __restrict__ Ph,
                                                    ushort* __restrict__ Pl, int causal) {
    __shared__ float red[4];
    int q = blockIdx.x, b = blockIdx.y;
    size_t base = ((size_t)b * S + q) * S;
    int valid = causal ? (q + 1) : S;
    int tid = threadIdx.x;
    float v[4];
    float mx = -3e38f;
#pragma unroll
    for (int j = 0; j < 4; j++) {
        int c = tid + j * 256;
        float x = (c < valid) ? Sc[base + c] : -3e38f;
        v[j] = x;
        mx = fmaxf(mx, v[j]);
    }
    for (int o = 32; o; o >>= 1) mx = fmaxf(mx, __shfl_xor(mx, o));
    if ((tid & 63) == 0) red[tid >> 6] = mx;
    __syncthreads();
    mx = fmaxf(fmaxf(red[0], red[1]), fmaxf(red[2], red[3]));
    float s = 0.f;
#pragma unroll
    for (int j = 0; j < 4; j++) {
        int c = tid + j * 256;
        float e = (c < valid) ? __expf(v[j] - mx) : 0.f;
        v[j] = e;
        s += e;
    }
    for (int o = 32; o; o >>= 1) s += __shfl_xor(s, o);
    __syncthreads();
    if ((tid & 63) == 0) red[tid >> 6] = s;
    __syncthreads();
    s = red[0] + red[1] + red[2] + red[3];
    float inv = 1.0f / s;
#pragma unroll
    for (int j = 0; j < 4; j++) {
        int c = tid + j * 256;
        float p = v[j] * inv;
        ushort h = f2bf(p);
        Ph[base + c] = h;
        Pl[base + c] = f2bf(p - bf2f(h));
    }
}

// ---- residual + layernorm: residual lives in h/l planes (f32 only for layer-0 in / final out) ----
__global__ __launch_bounds__(256) void ln_res(const ushort* __restrict__ xinh,
                                              const ushort* __restrict__ xinl,
                                              const float* __restrict__ xinf,
                                              const float* __restrict__ y,
                                              const float* __restrict__ g,
                                              const float* __restrict__ bta,
                                              float* __restrict__ xof,
                                              ushort* __restrict__ xh,
                                              ushort* __restrict__ xl) {
    __shared__ float red[4];
    int row = blockIdx.x;
    size_t base = (size_t)row * D;
    int tid = threadIdx.x;
    int c0 = tid * 4;
    float t[4];
    float4 yv = *(const float4*)&y[base + c0];
    if (xinf) {
        float4 xv = *(const float4*)&xinf[base + c0];
        t[0] = xv.x + yv.x; t[1] = xv.y + yv.y; t[2] = xv.z + yv.z; t[3] = xv.w + yv.w;
    } else {
        ushort4 hv = *(const ushort4*)&xinh[base + c0];
        ushort4 lv = *(const ushort4*)&xinl[base + c0];
        t[0] = bf2f(hv.x) + bf2f(lv.x) + yv.x;
        t[1] = bf2f(hv.y) + bf2f(lv.y) + yv.y;
        t[2] = bf2f(hv.z) + bf2f(lv.z) + yv.z;
        t[3] = bf2f(hv.w) + bf2f(lv.w) + yv.w;
    }
    float s = t[0] + t[1] + t[2] + t[3];
    for (int o = 32; o; o >>= 1) s += __shfl_xor(s, o);
    if ((tid & 63) == 0) red[tid >> 6] = s;
    __syncthreads();
    s = red[0] + red[1] + red[2] + red[3];
    float mean = s * (1.0f / D);
    float vs = 0.f;
#pragma unroll
    for (int j = 0; j < 4; j++) {
        float dd = t[j] - mean;
        vs += dd * dd;
    }
    for (int o = 32; o; o >>= 1) vs += __shfl_xor(vs, o);
    __syncthreads();
    if ((tid & 63) == 0) red[tid >> 6] = vs;
    __syncthreads();
    vs = red[0] + red[1] + red[2] + red[3];
    float inv = rsqrtf(vs * (1.0f / D) + 1e-5f);
    float4 gv = *(const float4*)&g[c0];
    float4 bv = *(const float4*)&bta[c0];
    float o0 = (t[0] - mean) * inv * gv.x + bv.x;
    float o1 = (t[1] - mean) * inv * gv.y + bv.y;
    float o2 = (t[2] - mean) * inv * gv.z + bv.z;
    float o3 = (t[3] - mean) * inv * gv.w + bv.w;
    if (xof) {
        float4 fo = {o0, o1, o2, o3};
        *(float4*)&xof[base + c0] = fo;
    }
    ushort4 h, l;
    h.x = f2bf(o0); l.x = f2bf(o0 - bf2f(h.x));
    h.y = f2bf(o1); l.y = f2bf(o1 - bf2f(h.y));
    h.z = f2bf(o2); l.z = f2bf(o2 - bf2f(h.z));
    h.w = f2bf(o3); l.w = f2bf(o3 - bf2f(h.w));
    *(ushort4*)&xh[base + c0] = h;
    *(ushort4*)&xl[base + c0] = l;
}

__global__ __launch_bounds__(256) void fill_f32(float* out, float v, int n) {
    int i = (blockIdx.x * 256 + threadIdx.x) * 4;
    if (i >= n) return;
    float4 f = {v, v, v, v};
    *(float4*)&out[i] = f;
}

extern "C" void kernel_launch(void* const* d_in, const int* in_sizes, int n_in,
                              void* d_out, int out_size, void* d_ws, size_t ws_size,
                              hipStream_t stream) {
    dim3 blk(256);
    const int M = BATCH * S;  // 4096
    const int fill_blocks = (out_size / 4 + 255) / 256;

    int base = n_in - 18;
    bool layout_ok = (base >= 2) && (out_size == M * D) &&
                     (in_sizes[0] == M * D) && (in_sizes[1] == M * D) &&
                     (in_sizes[base] == L * D * D) && (in_sizes[base + 4] == L * D) &&
                     (in_sizes[base + 12] == L * D * DFF) && (in_sizes[base + 13] == L * DFF);
    if (!layout_ok) {
        fill_f32<<<fill_blocks, blk, 0, stream>>>((float*)d_out, 9000.f, out_size);
        return;
    }
    const float* x_in = (const float*)d_in[0];
    const float* enc  = (const float*)d_in[1];
    const float* Wq1 = (const float*)d_in[base + 0];
    const float* Wk1 = (const float*)d_in[base + 1];
    const float* Wv1 = (const float*)d_in[base + 2];
    const float* Wo1 = (const float*)d_in[base + 3];
    const float* g1  = (const float*)d_in[base + 4];
    const float* b1  = (const float*)d_in[base + 5];
    const float* Wq2 = (const float*)d_in[base + 6];
    const float* Wk2 = (const float*)d_in[base + 7];
    const float* Wv2 = (const float*)d_in[base + 8];
    const float* Wo2 = (const float*)d_in[base + 9];
    const float* g2  = (const float*)d_in[base + 10];
    const float* b2  = (const float*)d_in[base + 11];
    const float* Wf1 = (const float*)d_in[base + 12];
    const float* bf1 = (const float*)d_in[base + 13];
    const float* Wf2 = (const float*)d_in[base + 14];
    const float* bf2 = (const float*)d_in[base + 15];
    const float* g3  = (const float*)d_in[base + 16];
    const float* b3  = (const float*)d_in[base + 17];

    const size_t PL = (size_t)M * D * 2;   // 8 MiB bf16 plane
    const size_t WB = (size_t)D * D * 2;   // 2 MiB weight plane
    const size_t required = 22 * PL;       // 176 MiB (unchanged, conservative)
    if (ws_size < required) {
        fill_f32<<<fill_blocks, blk, 0, stream>>>((float*)d_out, 500.f, out_size);
        return;
    }

    char* ws = (char*)d_ws;
    size_t off = 0;
    auto carve = [&](size_t bytes) -> char* {
        char* p = ws + off;
        off += (bytes + 255) & ~(size_t)255;
        return p;
    };
    ushort* xh = (ushort*)carve(PL);     // xh,eh adjacent; xl,el adjacent (z=2 cross)
    ushort* eh = (ushort*)carve(PL);
    ushort* xl = (ushort*)carve(PL);
    ushort* el = (ushort*)carve(PL);
    char*   clu = carve(10 * PL);        // 80 MiB scratch
    ushort* uvh = (ushort*)clu;                  // u|vo [M][2048] hi (16MB)
    ushort* uvl = (ushort*)(clu + 2 * PL);       // lo (16MB)
    ushort* vth = (ushort*)(clu + 4 * PL);       // vo^T [b][d][s] (8MB)
    ushort* vtl = (ushort*)(clu + 5 * PL);
    float*  scores = (float*)(clu + 6 * PL);     // 16MB
    ushort* Astkh = (ushort*)(clu + 6 * PL);     // weight-prep aliases
    ushort* Astkl = (ushort*)(clu + 7 * PL);
    ushort* Bstkh = (ushort*)(clu + 8 * PL);
    ushort* Bstkl = (ushort*)(clu + 9 * PL);
    float*  wpart = (float*)clu;                 // FFN: 32MB partials
    ushort* wf2Th = (ushort*)(clu + 4 * PL);
    ushort* wf2Tl = (ushort*)(clu + 5 * PL);
    ushort* wpH   = (ushort*)(clu + 6 * PL);
    ushort* wpL   = (ushort*)(clu + 6 * PL + WB);
    float*  bprime = (float*)(clu + 6 * PL + 2 * WB);
    ushort* ph = (ushort*)carve(PL);
    ushort* pl_ = (ushort*)carve(PL);
    float*  yf = (float*)carve(2 * PL);
    ushort* WTh = (ushort*)carve(PL);    // [4][D][D]: WqkT1, WvoT1, WqkT2, WvoT2
    ushort* WTl = (ushort*)carve(PL);

    auto gemm = [&](const ushort* Ah, const ushort* Al, const ushort* Bh, const ushort* Bl,
                    float* Cf, ushort* Ch, ushort* Cl, const float* bias, float alpha,
                    int gm, int gn, int gk, int lda, int ldb, int ldc,
                    long sA, long sB, long sC, int batch, int tri) {
        dim3 g(gn / 128, gm / 128, batch);
        gemm3<<<g, blk, 0, stream>>>(Ah, Al, Bh, Bl, Cf, Ch, Cl, bias, alpha,
                                     gm, gn, gk, lda, ldb, ldc, sA, sB, sC, tri);
    };
    auto cvtw = [&](const float* W, ushort* oh, ushort* ol) {
        cvt_split<<<(D * D) / 1024, blk, 0, stream>>>(W, oh, ol, D * D);
    };

    cvt_split<<<(M * D) / 1024, blk, 0, stream>>>(x_in, xh, xl, M * D);
    cvt_split<<<(M * D) / 1024, blk, 0, stream>>>(enc, eh, el, M * D);

    const long SM = (long)S * S;
    const long SD = (long)S * D;
    const long DD = (long)D * D;

    for (int i = 0; i < L; i++) {
        size_t wo = (size_t)i * D * D;
        // ===== weight prep: WqkT = Wk@Wq^T ; WvoT = Wo^T@Wv^T (batched z=4) =====
        cvtw(Wk1 + wo, Astkh + 0 * DD, Astkl + 0 * DD);
        transpose_w<<<dim3(D / 32, D / 32), blk, 0, stream>>>(Wo1 + wo, Astkh + 1 * DD, Astkl + 1 * DD, D, D);
        cvtw(Wk2 + wo, Astkh + 2 * DD, Astkl + 2 * DD);
        transpose_w<<<dim3(D / 32, D / 32), blk, 0, stream>>>(Wo2 + wo, Astkh + 3 * DD, Astkl + 3 * DD, D, D);
        cvtw(Wq1 + wo, Bstkh + 0 * DD, Bstkl + 0 * DD);
        cvtw(Wv1 + wo, Bstkh + 1 * DD, Bstkl + 1 * DD);
        cvtw(Wq2 + wo, Bstkh + 2 * DD, Bstkl + 2 * DD);
        cvtw(Wv2 + wo, Bstkh + 3 * DD, Bstkl + 3 * DD);
        gemm(Astkh, Astkl, Bstkh, Bstkl, nullptr, WTh, WTl, nullptr, 1.f,
             D, D, D, D, D, D, DD, DD, DD, 4, 0);

        // ===== self-attention (causal) =====
        gemm(xh, xl, WTh, WTl, nullptr, uvh, uvl, nullptr, 1.f,
             M, 2 * D, D, D, D, 2 * D, 0, 0, 0, 1, 0);
        vtrans<<<dim3(D / 32, S / 32, 2 * BATCH), blk, 0, stream>>>(uvh, uvl, vth, vtl, 2 * D, D);
        gemm(uvh, uvl, xh, xl, scores, nullptr, nullptr, nullptr, 0.125f,
             S, S, D, 2 * D, D, S, (long)S * 2 * D, SD, SM, BATCH, 1);
        softmax_rows<<<dim3(S, BATCH), blk, 0, stream>>>(scores, ph, pl_, 1);
        gemm(ph, pl_, vth, vtl, yf, nullptr, nullptr, nullptr, 1.f,
             S, D, S, S, S, D, SM, SD, SD, BATCH, 2);
        ln_res<<<M, blk, 0, stream>>>(xh, xl, (i == 0) ? x_in : nullptr, yf,
                                      g1 + (size_t)i * D, b1 + (size_t)i * D,
                                      nullptr, xh, xl);

        // ===== cross-attention =====
        gemm(xh, xl, WTh + 2 * DD, WTl + 2 * DD, nullptr, uvh, uvl, nullptr, 1.f,
             M, D, D, D, D, 2 * D, (long)M * D, DD, D, 2, 0);
        vtrans<<<dim3(D / 32, S / 32, 2 * BATCH), blk, 0, stream>>>(uvh, uvl, vth, vtl, 2 * D, D);
        gemm(uvh, uvl, eh, el, scores, nullptr, nullptr, nullptr, 0.125f,
             S, S, D, 2 * D, D, S, (long)S * 2 * D, SD, SM, BATCH, 0);
        softmax_rows<<<dim3(S, BATCH), blk, 0, stream>>>(scores, ph, pl_, 0);
        gemm(ph, pl_, vth, vtl, yf, nullptr, nullptr, nullptr, 1.f,
             S, D, S, S, S, D, SM, SD, SD, BATCH, 0);
        ln_res<<<M, blk, 0, stream>>>(xh, xl, nullptr, yf,
                                      g2 + (size_t)i * D, b2 + (size_t)i * D,
                                      nullptr, xh, xl);

        // ===== feedforward (collapsed) =====
        const float* Wf1i = Wf1 + (size_t)i * D * DFF;
        const float* Wf2i = Wf2 + (size_t)i * DFF * D;
        transpose_w<<<dim3(D / 32, DFF / 32), blk, 0, stream>>>(Wf2i, wf2Th, wf2Tl, DFF, D);
        cvt_split<<<(D * DFF) / 1024, blk, 0, stream>>>(Wf1i, ph, pl_, D * DFF);
        gemm(wf2Th, wf2Tl, ph, pl_, wpart, nullptr, nullptr, nullptr, 1.f,
             1024, 1024, 512, DFF, DFF, 1024, 512, 512, 1048576, 8, 0);
        reduce_split<<<1024, blk, 0, stream>>>(wpart, wpH, wpL);
        bias_fold<<<16, blk, 0, stream>>>(bf1 + (size_t)i * DFF, Wf2i,
                                          bf2 + (size_t)i * D, bprime);
        gemm(xh, xl, wpH, wpL, yf, nullptr, nullptr, bprime, 1.f,
             M, D, D, D, D, D, 0, 0, 0, 1, 0);
        ln_res<<<M, blk, 0, stream>>>(xh, xl, nullptr, yf,
                                      g3 + (size_t)i * D, b3 + (size_t)i * D,
                                      (i == L - 1) ? (float*)d_out : nullptr, xh, xl);
    }
}

// Round 20
// 2752.275 us; speedup vs baseline: 2.4722x; 1.0352x over previous
//
#include <hip/hip_runtime.h>

#define L 6
#define D 1024
#define DFF 4096
#define BATCH 4
#define S 1024

typedef __attribute__((ext_vector_type(4))) float f32x4;
typedef __attribute__((ext_vector_type(8))) short short8;

__device__ __forceinline__ ushort f2bf(float f) {
    unsigned int u = __float_as_uint(f);
    u = u + 0x7FFF + ((u >> 16) & 1);
    return (ushort)(u >> 16);
}
__device__ __forceinline__ float bf2f(ushort u) {
    return __uint_as_float(((unsigned int)u) << 16);
}
__device__ __forceinline__ void gload16(const ushort* g, ushort* l) {
    __builtin_amdgcn_global_load_lds(
        (const __attribute__((address_space(1))) void*)g,
        (__attribute__((address_space(3))) void*)l, 16, 0, 0);
}

// ---------------- split f32 -> (hi, lo) bf16 planes ----------------
__global__ __launch_bounds__(256) void cvt_split(const float* __restrict__ in,
                                                 ushort* __restrict__ oh,
                                                 ushort* __restrict__ ol, int n) {
    int i = (blockIdx.x * 256 + threadIdx.x) * 4;
    if (i >= n) return;
    float4 v = *(const float4*)&in[i];
    ushort4 h, l;
    h.x = f2bf(v.x); l.x = f2bf(v.x - bf2f(h.x));
    h.y = f2bf(v.y); l.y = f2bf(v.y - bf2f(h.y));
    h.z = f2bf(v.z); l.z = f2bf(v.z - bf2f(h.z));
    h.w = f2bf(v.w); l.w = f2bf(v.w - bf2f(h.w));
    *(ushort4*)&oh[i] = h;
    *(ushort4*)&ol[i] = l;
}

// ------- transpose weight [K,N] f32 -> [N,K] h/l bf16 -------
__global__ __launch_bounds__(256) void transpose_w(const float* __restrict__ W,
                                                   ushort* __restrict__ outh,
                                                   ushort* __restrict__ outl,
                                                   int K, int N) {
    __shared__ float T[32][33];
    int n0 = blockIdx.x * 32, k0 = blockIdx.y * 32;
    int t = threadIdx.x;
    int r = t >> 3, c4 = (t & 7) * 4;
    float4 v = *(const float4*)&W[(size_t)(k0 + r) * N + n0 + c4];
    T[r][c4 + 0] = v.x; T[r][c4 + 1] = v.y; T[r][c4 + 2] = v.z; T[r][c4 + 3] = v.w;
    __syncthreads();
    float a0 = T[c4 + 0][r], a1 = T[c4 + 1][r], a2 = T[c4 + 2][r], a3 = T[c4 + 3][r];
    ushort4 h, l;
    h.x = f2bf(a0); l.x = f2bf(a0 - bf2f(h.x));
    h.y = f2bf(a1); l.y = f2bf(a1 - bf2f(h.y));
    h.z = f2bf(a2); l.z = f2bf(a2 - bf2f(h.z));
    h.w = f2bf(a3); l.w = f2bf(a3 - bf2f(h.w));
    size_t ob = (size_t)(n0 + r) * K + k0 + c4;
    *(ushort4*)&outh[ob] = h;
    *(ushort4*)&outl[ob] = l;
}

// -------- prep8: batched per-layer weight prep (replaces 8 launches) --------
// z: 0..3 -> Astk[z] (1,3 transposed); 4..7 -> Bstk[z-4] (direct)
__global__ __launch_bounds__(256) void prep8(
    const float* __restrict__ W0, const float* __restrict__ W1,
    const float* __restrict__ W2, const float* __restrict__ W3,
    const float* __restrict__ W4, const float* __restrict__ W5,
    const float* __restrict__ W6, const float* __restrict__ W7,
    ushort* __restrict__ Ah, ushort* __restrict__ Al,
    ushort* __restrict__ Bh, ushort* __restrict__ Bl) {
    __shared__ float T[32][33];
    const int z = blockIdx.z;
    const float* W;
    switch (z) {
        case 0: W = W0; break; case 1: W = W1; break;
        case 2: W = W2; break; case 3: W = W3; break;
        case 4: W = W4; break; case 5: W = W5; break;
        case 6: W = W6; break; default: W = W7; break;
    }
    ushort* oh = (z < 4 ? Ah : Bh) + (size_t)(z & 3) * D * D;
    ushort* ol = (z < 4 ? Al : Bl) + (size_t)(z & 3) * D * D;
    const int n0 = blockIdx.x * 32, k0 = blockIdx.y * 32;
    const int t = threadIdx.x;
    const int r = t >> 3, c4 = (t & 7) * 4;
    float4 v = *(const float4*)&W[(size_t)(k0 + r) * D + n0 + c4];
    if (z == 1 || z == 3) {
        T[r][c4 + 0] = v.x; T[r][c4 + 1] = v.y; T[r][c4 + 2] = v.z; T[r][c4 + 3] = v.w;
        __syncthreads();
        float a0 = T[c4 + 0][r], a1 = T[c4 + 1][r], a2 = T[c4 + 2][r], a3 = T[c4 + 3][r];
        ushort4 h, l;
        h.x = f2bf(a0); l.x = f2bf(a0 - bf2f(h.x));
        h.y = f2bf(a1); l.y = f2bf(a1 - bf2f(h.y));
        h.z = f2bf(a2); l.z = f2bf(a2 - bf2f(h.z));
        h.w = f2bf(a3); l.w = f2bf(a3 - bf2f(h.w));
        size_t ob = (size_t)(n0 + r) * D + k0 + c4;
        *(ushort4*)&oh[ob] = h;
        *(ushort4*)&ol[ob] = l;
    } else {
        ushort4 h, l;
        h.x = f2bf(v.x); l.x = f2bf(v.x - bf2f(h.x));
        h.y = f2bf(v.y); l.y = f2bf(v.y - bf2f(h.y));
        h.z = f2bf(v.z); l.z = f2bf(v.z - bf2f(h.z));
        h.w = f2bf(v.w); l.w = f2bf(v.w - bf2f(h.w));
        size_t ob = (size_t)(k0 + r) * D + n0 + c4;
        *(ushort4*)&oh[ob] = h;
        *(ushort4*)&ol[ob] = l;
    }
}

// ---------------- transpose vo planes [b][s][2048-strided] -> [b][d][s] ----------------
__global__ __launch_bounds__(256) void vtrans(const ushort* __restrict__ inh,
                                              const ushort* __restrict__ inl,
                                              ushort* __restrict__ outh,
                                              ushort* __restrict__ outl,
                                              int ld_in, int col_off) {
    __shared__ ushort T[32][40];
    const int pz = blockIdx.z, b = pz >> 1;
    const ushort* in = (pz & 1) ? inl : inh;
    ushort* out = (pz & 1) ? outl : outh;
    const int d0 = blockIdx.x * 32, s0 = blockIdx.y * 32;
    const int t = threadIdx.x, r = t >> 3, c4 = (t & 7) * 4;
    ushort4 v = *(const ushort4*)&in[(size_t)(b * S + s0 + r) * ld_in + col_off + d0 + c4];
    T[r][c4 + 0] = v.x; T[r][c4 + 1] = v.y; T[r][c4 + 2] = v.z; T[r][c4 + 3] = v.w;
    __syncthreads();
    ushort4 o = {T[c4 + 0][r], T[c4 + 1][r], T[c4 + 2][r], T[c4 + 3][r]};
    *(ushort4*)&out[(size_t)(b * D + d0 + r) * S + s0 + c4] = o;
}

// -------- reduce 8 split-K partials -> h/l planes, + fused bias fold (blocks >= 1024) --------
__global__ __launch_bounds__(256) void reduce_bias(const float* __restrict__ part,
                                                   ushort* __restrict__ oh,
                                                   ushort* __restrict__ ol,
                                                   const float* __restrict__ bf1,
                                                   const float* __restrict__ Wf2,
                                                   const float* __restrict__ bf2,
                                                   float* __restrict__ bout) {
    if (blockIdx.x < 1024) {
        int i = (blockIdx.x * 256 + threadIdx.x) * 4;
        float4 s = *(const float4*)&part[i];
#pragma unroll
        for (int z = 1; z < 8; z++) {
            float4 p = *(const float4*)&part[(size_t)z * 1048576 + i];
            s.x += p.x; s.y += p.y; s.z += p.z; s.w += p.w;
        }
        ushort4 h, l;
        h.x = f2bf(s.x); l.x = f2bf(s.x - bf2f(h.x));
        h.y = f2bf(s.y); l.y = f2bf(s.y - bf2f(h.y));
        h.z = f2bf(s.z); l.z = f2bf(s.z - bf2f(h.z));
        h.w = f2bf(s.w); l.w = f2bf(s.w - bf2f(h.w));
        *(ushort4*)&oh[i] = h;
        *(ushort4*)&ol[i] = l;
    } else {
        __shared__ float red[4][64];
        const int lane = threadIdx.x & 63, js = threadIdx.x >> 6;
        const int n = (blockIdx.x - 1024) * 64 + lane;
        float s = 0.f;
        const int j0 = js * 1024;
        for (int j = j0; j < j0 + 1024; j++) s += bf1[j] * Wf2[(size_t)j * D + n];
        red[js][lane] = s;
        __syncthreads();
        if (js == 0)
            bout[n] = red[0][lane] + red[1][lane] + red[2][lane] + red[3][lane] + bf2[n];
    }
}

// ---------------- gemm3: 128x128 split-precision GEMM (proven K-loop) ----------------
// bf16 output path stages C in LDS and writes back fully coalesced.
// triMode: 0 none; 1 = causal scores (skip bx>by); 2 = causal PV (cap K-tiles)
__global__ __launch_bounds__(256) void gemm3(
    const ushort* __restrict__ Ah, const ushort* __restrict__ Al,
    const ushort* __restrict__ Bh, const ushort* __restrict__ Bl,
    float* __restrict__ Cf, ushort* __restrict__ Ch, ushort* __restrict__ Cl,
    const float* __restrict__ bias, float alpha,
    int M, int N, int K, int lda, int ldb, int ldc,
    long sA, long sB, long sC, int triMode) {
    __shared__ ushort lds[4 * 128 * 64];   // 64 KiB (staging; reused for C-tile)
    ushort* Ash = lds;
    ushort* Asl = lds + 128 * 64;
    ushort* Bsh = lds + 2 * 128 * 64;
    ushort* Bsl = lds + 3 * 128 * 64;

    const int gx = gridDim.x, gy = gridDim.y;
    int nblk = gx * gy * gridDim.z;
    int bid = (blockIdx.z * gy + blockIdx.y) * gx + blockIdx.x;
    if ((nblk & 7) == 0) bid = (bid & 7) * (nblk >> 3) + (bid >> 3);
    const int bx = bid % gx;
    int rem = bid / gx;
    const int by = rem % gy;
    const int z = rem / gy;

    if (triMode == 1 && bx > by) return;
    int NT = K >> 6;
    if (triMode == 2) {
        int cap = 2 * by + 2;
        if (cap < NT) NT = cap;
    }

    const int bm = by * 128, bn = bx * 128;
    const ushort* A0 = Ah + (size_t)z * sA;
    const ushort* A1 = Al + (size_t)z * sA;
    const ushort* B0 = Bh + (size_t)z * sB;
    const ushort* B1 = Bl + (size_t)z * sB;
    const size_t coff = (size_t)z * sC;

    const int tid = threadIdx.x, lane = tid & 63;
    const int wid = tid >> 6, wr = wid >> 1, wc = wid & 1;
    const int lr = lane & 15, lg = lane >> 4;

    f32x4 acc[4][4] = {};

    for (int kt = 0; kt < NT; kt++) {
        const int k0 = kt << 6;
        if (kt) __syncthreads();
#pragma unroll
        for (int c = 0; c < 4; c++) {
            const int idx = c * 256 + tid;
            const int row = idx >> 3;
            const int col = (((idx & 7) ^ (row & 7)) * 8);
            const int lbase = (c * 256 + (tid & 192)) * 8;
            const size_t aoff = (size_t)(bm + row) * lda + k0 + col;
            const size_t boff = (size_t)(bn + row) * ldb + k0 + col;
            gload16(A0 + aoff, Ash + lbase);
            gload16(A1 + aoff, Asl + lbase);
            gload16(B0 + boff, Bsh + lbase);
            gload16(B1 + boff, Bsl + lbase);
        }
        asm volatile("s_waitcnt vmcnt(0)" ::: "memory");
        __syncthreads();
#pragma unroll
        for (int ks = 0; ks < 2; ks++) {
            short8 afh[4], afl[4], bfh[4], bfl[4];
#pragma unroll
            for (int i = 0; i < 4; i++) {
                const int arow = wr * 64 + i * 16 + lr;
                const int brow = wc * 64 + i * 16 + lr;
                const int ar = arow * 64 + ((ks * 4 + lg) ^ (arow & 7)) * 8;
                const int br = brow * 64 + ((ks * 4 + lg) ^ (brow & 7)) * 8;
                afh[i] = *(const short8*)&Ash[ar];
                afl[i] = *(const short8*)&Asl[ar];
                bfh[i] = *(const short8*)&Bsh[br];
                bfl[i] = *(const short8*)&Bsl[br];
            }
#pragma unroll
            for (int i = 0; i < 4; i++)
#pragma unroll
                for (int j = 0; j < 4; j++) {
                    acc[i][j] = __builtin_amdgcn_mfma_f32_16x16x32_bf16(afh[i], bfh[j], acc[i][j], 0, 0, 0);
                    acc[i][j] = __builtin_amdgcn_mfma_f32_16x16x32_bf16(afh[i], bfl[j], acc[i][j], 0, 0, 0);
                    acc[i][j] = __builtin_amdgcn_mfma_f32_16x16x32_bf16(afl[i], bfh[j], acc[i][j], 0, 0, 0);
                }
        }
    }
    if (Ch) {
        __syncthreads();
        uint* lds32 = (uint*)lds;            // [128][128] u32 = 64 KiB
#pragma unroll
        for (int j = 0; j < 4; j++) {
            const int n = wc * 64 + j * 16 + lr;
            const float bv = bias ? bias[bn + n] : 0.f;
#pragma unroll
            for (int i = 0; i < 4; i++) {
#pragma unroll
                for (int r = 0; r < 4; r++) {
                    const int m = wr * 64 + i * 16 + lg * 4 + r;
                    float v = acc[i][j][r] * alpha + bv;
                    ushort h = f2bf(v);
                    ushort l2 = f2bf(v - bf2f(h));
                    lds32[m * 128 + n] = (uint)h | ((uint)l2 << 16);
                }
            }
        }
        __syncthreads();
#pragma unroll
        for (int it = 0; it < 16; it++) {
            const int flat = it * 1024 + tid * 4;
            const int row = flat >> 7, colc = flat & 127;
            uint4 p = *(const uint4*)&lds32[flat];
            ushort4 hh, ll;
            hh.x = (ushort)p.x; ll.x = (ushort)(p.x >> 16);
            hh.y = (ushort)p.y; ll.y = (ushort)(p.y >> 16);
            hh.z = (ushort)p.z; ll.z = (ushort)(p.z >> 16);
            hh.w = (ushort)p.w; ll.w = (ushort)(p.w >> 16);
            const size_t cio = coff + (size_t)(bm + row) * ldc + bn + colc;
            *(ushort4*)&Ch[cio] = hh;
            *(ushort4*)&Cl[cio] = ll;
        }
    } else {
#pragma unroll
        for (int j = 0; j < 4; j++) {
            const int n = bn + wc * 64 + j * 16 + lr;
            const float bv = bias ? bias[n] : 0.f;
#pragma unroll
            for (int i = 0; i < 4; i++) {
#pragma unroll
                for (int r = 0; r < 4; r++) {
                    const int m = bm + wr * 64 + i * 16 + lg * 4 + r;
                    Cf[coff + (size_t)m * ldc + n] = acc[i][j][r] * alpha + bv;
                }
            }
        }
    }
}

// ---------------- row softmax (f32 in, h/l bf16 planes out) ----------------
__global__ __launch_bounds__(256) void softmax_rows(const float* __restrict__ Sc,
                                                    ushort* __restrict__ Ph,
                                                    ushort* __restrict__ Pl, int causal) {
    __shared__ float red[4];
    int q = blockIdx.x, b = blockIdx.y;
    size_t base = ((size_t)b * S + q) * S;
    int valid = causal ? (q + 1) : S;
    int tid = threadIdx.x;
    float v[4];
    float mx = -3e38f;
#pragma unroll
    for (int j = 0; j < 4; j++) {
        int c = tid + j * 256;
        float x = (c < valid) ? Sc[base + c] : -3e38f;
        v[j] = x;
        mx = fmaxf(mx, v[j]);
    }
    for (int o = 32; o; o >>= 1) mx = fmaxf(mx, __shfl_xor(mx, o));
    if ((tid & 63) == 0) red[tid >> 6] = mx;
    __syncthreads();
    mx = fmaxf(fmaxf(red[0], red[1]), fmaxf(red[2], red[3]));
    float s = 0.f;
#pragma unroll
    for (int j = 0; j < 4; j++) {
        int c = tid + j * 256;
        float e = (c < valid) ? __expf(v[j] - mx) : 0.f;
        v[j] = e;
        s += e;
    }
    for (int o = 32; o; o >>= 1) s += __shfl_xor(s, o);
    __syncthreads();
    if ((tid & 63) == 0) red[tid >> 6] = s;
    __syncthreads();
    s = red[0] + red[1] + red[2] + red[3];
    float inv = 1.0f / s;
#pragma unroll
    for (int j = 0; j < 4; j++) {
        int c = tid + j * 256;
        float p = v[j] * inv;
        ushort h = f2bf(p);
        Ph[base + c] = h;
        Pl[base + c] = f2bf(p - bf2f(h));
    }
}

// ---- residual + layernorm: residual lives in h/l planes (f32 only for layer-0 in / final out) ----
__global__ __launch_bounds__(256) void ln_res(const ushort* __restrict__ xinh,
                                              const ushort* __restrict__ xinl,
                                              const float* __restrict__ xinf,
                                              const float* __restrict__ y,
                                              const float* __restrict__ g,
                                              const float* __restrict__ bta,
                                              float* __restrict__ xof,
                                              ushort* __restrict__ xh,
                                              ushort* __restrict__ xl) {
    __shared__ float red[4];
    int row = blockIdx.x;
    size_t base = (size_t)row * D;
    int tid = threadIdx.x;
    int c0 = tid * 4;
    float t[4];
    float4 yv = *(const float4*)&y[base + c0];
    if (xinf) {
        float4 xv = *(const float4*)&xinf[base + c0];
        t[0] = xv.x + yv.x; t[1] = xv.y + yv.y; t[2] = xv.z + yv.z; t[3] = xv.w + yv.w;
    } else {
        ushort4 hv = *(const ushort4*)&xinh[base + c0];
        ushort4 lv = *(const ushort4*)&xinl[base + c0];
        t[0] = bf2f(hv.x) + bf2f(lv.x) + yv.x;
        t[1] = bf2f(hv.y) + bf2f(lv.y) + yv.y;
        t[2] = bf2f(hv.z) + bf2f(lv.z) + yv.z;
        t[3] = bf2f(hv.w) + bf2f(lv.w) + yv.w;
    }
    float s = t[0] + t[1] + t[2] + t[3];
    for (int o = 32; o; o >>= 1) s += __shfl_xor(s, o);
    if ((tid & 63) == 0) red[tid >> 6] = s;
    __syncthreads();
    s = red[0] + red[1] + red[2] + red[3];
    float mean = s * (1.0f / D);
    float vs = 0.f;
#pragma unroll
    for (int j = 0; j < 4; j++) {
        float dd = t[j] - mean;
        vs += dd * dd;
    }
    for (int o = 32; o; o >>= 1) vs += __shfl_xor(vs, o);
    __syncthreads();
    if ((tid & 63) == 0) red[tid >> 6] = vs;
    __syncthreads();
    vs = red[0] + red[1] + red[2] + red[3];
    float inv = rsqrtf(vs * (1.0f / D) + 1e-5f);
    float4 gv = *(const float4*)&g[c0];
    float4 bv = *(const float4*)&bta[c0];
    float o0 = (t[0] - mean) * inv * gv.x + bv.x;
    float o1 = (t[1] - mean) * inv * gv.y + bv.y;
    float o2 = (t[2] - mean) * inv * gv.z + bv.z;
    float o3 = (t[3] - mean) * inv * gv.w + bv.w;
    if (xof) {
        float4 fo = {o0, o1, o2, o3};
        *(float4*)&xof[base + c0] = fo;
    }
    ushort4 h, l;
    h.x = f2bf(o0); l.x = f2bf(o0 - bf2f(h.x));
    h.y = f2bf(o1); l.y = f2bf(o1 - bf2f(h.y));
    h.z = f2bf(o2); l.z = f2bf(o2 - bf2f(h.z));
    h.w = f2bf(o3); l.w = f2bf(o3 - bf2f(h.w));
    *(ushort4*)&xh[base + c0] = h;
    *(ushort4*)&xl[base + c0] = l;
}

__global__ __launch_bounds__(256) void fill_f32(float* out, float v, int n) {
    int i = (blockIdx.x * 256 + threadIdx.x) * 4;
    if (i >= n) return;
    float4 f = {v, v, v, v};
    *(float4*)&out[i] = f;
}

extern "C" void kernel_launch(void* const* d_in, const int* in_sizes, int n_in,
                              void* d_out, int out_size, void* d_ws, size_t ws_size,
                              hipStream_t stream) {
    dim3 blk(256);
    const int M = BATCH * S;  // 4096
    const int fill_blocks = (out_size / 4 + 255) / 256;

    int base = n_in - 18;
    bool layout_ok = (base >= 2) && (out_size == M * D) &&
                     (in_sizes[0] == M * D) && (in_sizes[1] == M * D) &&
                     (in_sizes[base] == L * D * D) && (in_sizes[base + 4] == L * D) &&
                     (in_sizes[base + 12] == L * D * DFF) && (in_sizes[base + 13] == L * DFF);
    if (!layout_ok) {
        fill_f32<<<fill_blocks, blk, 0, stream>>>((float*)d_out, 9000.f, out_size);
        return;
    }
    const float* x_in = (const float*)d_in[0];
    const float* enc  = (const float*)d_in[1];
    const float* Wq1 = (const float*)d_in[base + 0];
    const float* Wk1 = (const float*)d_in[base + 1];
    const float* Wv1 = (const float*)d_in[base + 2];
    const float* Wo1 = (const float*)d_in[base + 3];
    const float* g1  = (const float*)d_in[base + 4];
    const float* b1  = (const float*)d_in[base + 5];
    const float* Wq2 = (const float*)d_in[base + 6];
    const float* Wk2 = (const float*)d_in[base + 7];
    const float* Wv2 = (const float*)d_in[base + 8];
    const float* Wo2 = (const float*)d_in[base + 9];
    const float* g2  = (const float*)d_in[base + 10];
    const float* b2  = (const float*)d_in[base + 11];
    const float* Wf1 = (const float*)d_in[base + 12];
    const float* bf1 = (const float*)d_in[base + 13];
    const float* Wf2 = (const float*)d_in[base + 14];
    const float* bf2 = (const float*)d_in[base + 15];
    const float* g3  = (const float*)d_in[base + 16];
    const float* b3  = (const float*)d_in[base + 17];

    const size_t PL = (size_t)M * D * 2;   // 8 MiB bf16 plane
    const size_t WB = (size_t)D * D * 2;   // 2 MiB weight plane
    const size_t required = 22 * PL;       // 176 MiB
    if (ws_size < required) {
        fill_f32<<<fill_blocks, blk, 0, stream>>>((float*)d_out, 500.f, out_size);
        return;
    }

    char* ws = (char*)d_ws;
    size_t off = 0;
    auto carve = [&](size_t bytes) -> char* {
        char* p = ws + off;
        off += (bytes + 255) & ~(size_t)255;
        return p;
    };
    ushort* xh = (ushort*)carve(PL);     // xh,eh adjacent; xl,el adjacent (z=2 cross)
    ushort* eh = (ushort*)carve(PL);
    ushort* xl = (ushort*)carve(PL);
    ushort* el = (ushort*)carve(PL);
    char*   clu = carve(10 * PL);        // 80 MiB scratch
    ushort* uvh = (ushort*)clu;                  // u|vo [M][2048] hi (16MB)
    ushort* uvl = (ushort*)(clu + 2 * PL);       // lo (16MB)
    ushort* vth = (ushort*)(clu + 4 * PL);       // vo^T [b][d][s] (8MB)
    ushort* vtl = (ushort*)(clu + 5 * PL);
    float*  scores = (float*)(clu + 6 * PL);     // 16MB
    ushort* Astkh = (ushort*)(clu + 6 * PL);     // weight-prep aliases
    ushort* Astkl = (ushort*)(clu + 7 * PL);
    ushort* Bstkh = (ushort*)(clu + 8 * PL);
    ushort* Bstkl = (ushort*)(clu + 9 * PL);
    float*  wpart = (float*)clu;                 // FFN: 32MB partials
    ushort* wf2Th = (ushort*)(clu + 4 * PL);
    ushort* wf2Tl = (ushort*)(clu + 5 * PL);
    ushort* wpH   = (ushort*)(clu + 6 * PL);
    ushort* wpL   = (ushort*)(clu + 6 * PL + WB);
    float*  bprime = (float*)(clu + 6 * PL + 2 * WB);
    ushort* ph = (ushort*)carve(PL);
    ushort* pl_ = (ushort*)carve(PL);
    float*  yf = (float*)carve(2 * PL);
    ushort* WTh = (ushort*)carve(PL);    // [4][D][D]: WqkT1, WvoT1, WqkT2, WvoT2
    ushort* WTl = (ushort*)carve(PL);

    auto gemm = [&](const ushort* Ah, const ushort* Al, const ushort* Bh, const ushort* Bl,
                    float* Cf, ushort* Ch, ushort* Cl, const float* bias, float alpha,
                    int gm, int gn, int gk, int lda, int ldb, int ldc,
                    long sA, long sB, long sC, int batch, int tri) {
        dim3 g(gn / 128, gm / 128, batch);
        gemm3<<<g, blk, 0, stream>>>(Ah, Al, Bh, Bl, Cf, Ch, Cl, bias, alpha,
                                     gm, gn, gk, lda, ldb, ldc, sA, sB, sC, tri);
    };

    cvt_split<<<(M * D) / 1024, blk, 0, stream>>>(x_in, xh, xl, M * D);
    cvt_split<<<(M * D) / 1024, blk, 0, stream>>>(enc, eh, el, M * D);

    const long SM = (long)S * S;
    const long SD = (long)S * D;
    const long DD = (long)D * D;

    for (int i = 0; i < L; i++) {
        size_t wo = (size_t)i * D * D;
        // ===== weight prep (single batched launch): WqkT = Wk@Wq^T ; WvoT = Wo^T@Wv^T =====
        prep8<<<dim3(D / 32, D / 32, 8), blk, 0, stream>>>(
            Wk1 + wo, Wo1 + wo, Wk2 + wo, Wo2 + wo,
            Wq1 + wo, Wv1 + wo, Wq2 + wo, Wv2 + wo,
            Astkh, Astkl, Bstkh, Bstkl);
        gemm(Astkh, Astkl, Bstkh, Bstkl, nullptr, WTh, WTl, nullptr, 1.f,
             D, D, D, D, D, D, DD, DD, DD, 4, 0);

        // ===== self-attention (causal) =====
        gemm(xh, xl, WTh, WTl, nullptr, uvh, uvl, nullptr, 1.f,
             M, 2 * D, D, D, D, 2 * D, 0, 0, 0, 1, 0);
        vtrans<<<dim3(D / 32, S / 32, 2 * BATCH), blk, 0, stream>>>(uvh, uvl, vth, vtl, 2 * D, D);
        gemm(uvh, uvl, xh, xl, scores, nullptr, nullptr, nullptr, 0.125f,
             S, S, D, 2 * D, D, S, (long)S * 2 * D, SD, SM, BATCH, 1);
        softmax_rows<<<dim3(S, BATCH), blk, 0, stream>>>(scores, ph, pl_, 1);
        gemm(ph, pl_, vth, vtl, yf, nullptr, nullptr, nullptr, 1.f,
             S, D, S, S, S, D, SM, SD, SD, BATCH, 2);
        ln_res<<<M, blk, 0, stream>>>(xh, xl, (i == 0) ? x_in : nullptr, yf,
                                      g1 + (size_t)i * D, b1 + (size_t)i * D,
                                      nullptr, xh, xl);

        // ===== cross-attention =====
        gemm(xh, xl, WTh + 2 * DD, WTl + 2 * DD, nullptr, uvh, uvl, nullptr, 1.f,
             M, D, D, D, D, 2 * D, (long)M * D, DD, D, 2, 0);
        vtrans<<<dim3(D / 32, S / 32, 2 * BATCH), blk, 0, stream>>>(uvh, uvl, vth, vtl, 2 * D, D);
        gemm(uvh, uvl, eh, el, scores, nullptr, nullptr, nullptr, 0.125f,
             S, S, D, 2 * D, D, S, (long)S * 2 * D, SD, SM, BATCH, 0);
        softmax_rows<<<dim3(S, BATCH), blk, 0, stream>>>(scores, ph, pl_, 0);
        gemm(ph, pl_, vth, vtl, yf, nullptr, nullptr, nullptr, 1.f,
             S, D, S, S, S, D, SM, SD, SD, BATCH, 0);
        ln_res<<<M, blk, 0, stream>>>(xh, xl, nullptr, yf,
                                      g2 + (size_t)i * D, b2 + (size_t)i * D,
                                      nullptr, xh, xl);

        // ===== feedforward (collapsed) =====
        const float* Wf1i = Wf1 + (size_t)i * D * DFF;
        const float* Wf2i = Wf2 + (size_t)i * DFF * D;
        transpose_w<<<dim3(D / 32, DFF / 32), blk, 0, stream>>>(Wf2i, wf2Th, wf2Tl, DFF, D);
        cvt_split<<<(D * DFF) / 1024, blk, 0, stream>>>(Wf1i, ph, pl_, D * DFF);
        gemm(wf2Th, wf2Tl, ph, pl_, wpart, nullptr, nullptr, nullptr, 1.f,
             1024, 1024, 512, DFF, DFF, 1024, 512, 512, 1048576, 8, 0);
        reduce_bias<<<1040, blk, 0, stream>>>(wpart, wpH, wpL,
                                              bf1 + (size_t)i * DFF, Wf2i,
                                              bf2 + (size_t)i * D, bprime);
        gemm(xh, xl, wpH, wpL, yf, nullptr, nullptr, bprime, 1.f,
             M, D, D, D, D, D, 0, 0, 0, 1, 0);
        ln_res<<<M, blk, 0, stream>>>(xh, xl, nullptr, yf,
                                      g3 + (size_t)i * D, b3 + (size_t)i * D,
                                      (i == L - 1) ? (float*)d_out : nullptr, xh, xl);
    }
}